// Round 3
// baseline (1067.554 us; speedup 1.0000x reference)
//
#include <hip/hip_runtime.h>

typedef unsigned short u16;
typedef __attribute__((ext_vector_type(4))) float          f32x4;
typedef __attribute__((ext_vector_type(8))) short          bf8;
typedef __attribute__((ext_vector_type(8))) unsigned short us8;
typedef __attribute__((ext_vector_type(4))) unsigned short us4;

#define BATCH 8
#define CIN   320
#define COUT  256
#define NPIX  16384
#define NCLS  21
#define MTOT  (BATCH*NPIX)   // 131072
#define SROW  320            // u16 elements per SX row (s^T, later x / s_bar in first 256)

__device__ __forceinline__ float bf2f(u16 v){
    unsigned int u = ((unsigned int)v) << 16;
    float f; __builtin_memcpy(&f, &u, 4); return f;
}
__device__ __forceinline__ u16 f2bf(float f){
    unsigned int u; __builtin_memcpy(&u, &f, 4);
    u += 0x7fffu + ((u >> 16) & 1u);
    return (u16)(u >> 16);
}

// ---------- K0: W fp32 [256][320] -> bf16 same layout ----------
__global__ void k0_wcvt(const float* __restrict__ W, u16* __restrict__ Wbf){
    int i4 = blockIdx.x * 256 + threadIdx.x;   // 20480 float4s exactly
    float4 v = reinterpret_cast<const float4*>(W)[i4];
    us4 o;
    o[0] = f2bf(v.x); o[1] = f2bf(v.y); o[2] = f2bf(v.z); o[3] = f2bf(v.w);
    reinterpret_cast<us4*>(Wbf)[i4] = o;
}

// ---------- KT: s_feat fp32 [b][320][P] -> SX bf16 [b*P][SROW] (transposed) ----------
__global__ __launch_bounds__(256) void kt_strans(const float* __restrict__ in, u16* __restrict__ out){
    __shared__ float tile[64*65];
    const int t  = threadIdx.x;
    const int bid = blockIdx.x;
    const int pt = bid & 255;          // 256 p-tiles of 64
    const int ct = (bid >> 8) % 5;     // 5 c-tiles of 64
    const int b  = bid / (256*5);
    const float* src = in + ((size_t)b*CIN + ct*64)*NPIX + pt*64;
    #pragma unroll
    for (int it = 0; it < 4; it++){
        int f = it*256 + t;
        int i = f >> 4, c4 = f & 15;
        float4 v = *reinterpret_cast<const float4*>(src + (size_t)i*NPIX + c4*4);
        float* d = &tile[i*65 + c4*4];
        d[0]=v.x; d[1]=v.y; d[2]=v.z; d[3]=v.w;
    }
    __syncthreads();
    u16* dst = out + ((size_t)(b*NPIX + pt*64))*SROW + ct*64;
    #pragma unroll
    for (int it = 0; it < 2; it++){
        int f = it*256 + t;
        int p = f >> 3, c8 = f & 7;
        us8 o;
        #pragma unroll
        for (int j = 0; j < 8; j++) o[j] = f2bf(tile[(c8*8+j)*65 + p]);
        *reinterpret_cast<us8*>(dst + (size_t)p*SROW + c8*8) = o;
    }
}

// ---------- K1: MFMA GEMM x[p][o] = sum_c SX[p][c]*W[o][c]; writes x bf16 in place; BN sums ----------
__global__ __launch_bounds__(256) void k1_mfma(u16* SX, const u16* __restrict__ Wbf,
                                               float* __restrict__ bnsum, float* __restrict__ bnsumsq){
    __shared__ __align__(16) char sm[67584];   // K-loop: Sa[128 rows][128B swizzled]; epilogue: Xs[128][264] bf16
    __shared__ float bns[512];
    const int t = threadIdx.x;
    const int wid = t >> 6, l = t & 63;
    const size_t pblk = (size_t)blockIdx.x * 128;
    const int wm = (wid & 1) * 64;     // m (pixel) offset of wave
    const int wn = (wid >> 1) * 128;   // n (channel) offset of wave
    bns[t] = 0.f; bns[t+256] = 0.f;

    f32x4 acc[4][8];
    #pragma unroll
    for (int mi = 0; mi < 4; mi++)
        #pragma unroll
        for (int ni = 0; ni < 8; ni++)
            acc[mi][ni] = (f32x4){0.f,0.f,0.f,0.f};

    // staging: thread -> (row sp(+32*it), 16B chunk sg)
    const int sg = t & 7, sp = t >> 3;
    const u16* srcb = SX + (pblk + sp) * SROW + sg * 8;
    us8 stg[4];
    #pragma unroll
    for (int it = 0; it < 4; it++)
        stg[it] = *reinterpret_cast<const us8*>(srcb + (size_t)it*32*SROW);

    for (int kt = 0; kt < 5; kt++){
        __syncthreads();                       // LDS free (prev compute done)
        #pragma unroll
        for (int it = 0; it < 4; it++){        // regs -> swizzled LDS
            int p = sp + it*32;
            int byt = p*128 + ((sg*16) ^ ((p&7)<<4));
            *reinterpret_cast<us8*>(&sm[byt]) = stg[it];
        }
        if (kt < 4){                           // prefetch next K-tile (overlaps compute)
            #pragma unroll
            for (int it = 0; it < 4; it++)
                stg[it] = *reinterpret_cast<const us8*>(srcb + (size_t)it*32*SROW + (kt+1)*64);
        }
        __syncthreads();                       // tile ready
        #pragma unroll
        for (int ks = 0; ks < 2; ks++){
            bf8 bfr[8], afr[4];
            const u16* wp = Wbf + (size_t)(wn + (l & 15)) * CIN + kt*64 + ks*32 + (l >> 4)*8;
            #pragma unroll
            for (int ni = 0; ni < 8; ni++)
                bfr[ni] = *reinterpret_cast<const bf8*>(wp + (size_t)ni*16*CIN);
            #pragma unroll
            for (int mi = 0; mi < 4; mi++){
                int p = wm + mi*16 + (l & 15);
                int byt = p*128 + (((ks*4 + (l>>4))*16) ^ ((p&7)<<4));
                afr[mi] = *reinterpret_cast<const bf8*>(&sm[byt]);
            }
            #pragma unroll
            for (int mi = 0; mi < 4; mi++)
                #pragma unroll
                for (int ni = 0; ni < 8; ni++)
                    acc[mi][ni] = __builtin_amdgcn_mfma_f32_16x16x32_bf16(afr[mi], bfr[ni], acc[mi][ni], 0, 0, 0);
        }
    }
    __syncthreads();
    // acc -> Xs [128][264] bf16 (padded to keep writes ~conflict-free, rows 16B-aligned)
    #pragma unroll
    for (int mi = 0; mi < 4; mi++)
        #pragma unroll
        for (int ni = 0; ni < 8; ni++)
            #pragma unroll
            for (int r = 0; r < 4; r++){
                int p = wm + mi*16 + (l>>4)*4 + r;
                int o = wn + ni*16 + (l&15);
                *reinterpret_cast<u16*>(&sm[(p*264 + o)*2]) = f2bf(acc[mi][ni][r]);
            }
    __syncthreads();
    // coalesced readback -> global (in place over SX rows, stride SROW) + BN partial sums
    float s1[8], s2[8];
    #pragma unroll
    for (int j = 0; j < 8; j++){ s1[j] = 0.f; s2[j] = 0.f; }
    const int oc = (t & 31) * 8;
    const int pr = t >> 5;
    #pragma unroll
    for (int it = 0; it < 16; it++){
        int p = pr + it*8;
        us8 v = *reinterpret_cast<const us8*>(&sm[(p*264 + oc)*2]);
        *reinterpret_cast<us8*>(SX + (pblk + p)*SROW + oc) = v;
        #pragma unroll
        for (int j = 0; j < 8; j++){
            float fv = bf2f(v[j]);
            s1[j] += fv; s2[j] += fv*fv;
        }
    }
    #pragma unroll
    for (int j = 0; j < 8; j++){
        atomicAdd(&bns[oc + j],       s1[j]);
        atomicAdd(&bns[256 + oc + j], s2[j]);
    }
    __syncthreads();
    atomicAdd(&bnsum[t],   bns[t]);
    atomicAdd(&bnsumsq[t], bns[t + 256]);
}

// ---------- K2: BN affine coefficients ----------
__global__ void k2_bn(const float* __restrict__ bnsum, const float* __restrict__ bnsumsq,
                      const float* __restrict__ gamma, const float* __restrict__ beta,
                      float* __restrict__ bna, float* __restrict__ bnb){
    int o = threadIdx.x;
    float m = bnsum[o] / (float)MTOT;
    float v = bnsumsq[o] / (float)MTOT - m * m;
    float a = gamma[o] / sqrtf(v + 1e-5f);
    bna[o] = a;
    bnb[o] = beta[o] - m * a;
}

// ---------- K3: per-batch class histogram ----------
__global__ void k3_counts(const int* __restrict__ gt, float* __restrict__ counts){
    __shared__ float h[NCLS];
    int b = blockIdx.x, t = threadIdx.x;
    if (t < NCLS) h[t] = 0.f;
    __syncthreads();
    for (int i = t; i < NPIX; i += 256) atomicAdd(&h[gt[b * NPIX + i]], 1.0f);
    __syncthreads();
    if (t < NCLS) counts[b * NCLS + t] = h[t];
}

// ---------- K4a: BN+ReLU+l2norm -> s_bar in place; class stats (s) ----------
__global__ __launch_bounds__(512) void k4a(u16* SX, const int* __restrict__ gt,
                                           const float* __restrict__ bna, const float* __restrict__ bnb,
                                           float* __restrict__ gsum_s, float* __restrict__ gsumsq_s){
    __shared__ float lsum[NCLS*COUT];
    __shared__ float lsq [NCLS*COUT];
    const int t = threadIdx.x, wid = t >> 6, l = t & 63;
    const int b  = blockIdx.x >> 5;
    const int pb = (blockIdx.x & 31) * 512 + wid * 64;   // 64 pixels per wave
    for (int i = t; i < NCLS*COUT; i += 512){ lsum[i] = 0.f; lsq[i] = 0.f; }
    const float a0 = bna[l], a1 = bna[l+64], a2 = bna[l+128], a3 = bna[l+192];
    const float c0 = bnb[l], c1 = bnb[l+64], c2 = bnb[l+128], c3 = bnb[l+192];
    __syncthreads();
    const size_t p0 = (size_t)b * NPIX + pb;
    for (int pp = 0; pp < 64; pp++){
        size_t p = p0 + pp;
        u16* row = SX + p * SROW;
        float s0 = fmaxf(fmaf(a0, bf2f(row[l]),     c0), 0.f);
        float s1 = fmaxf(fmaf(a1, bf2f(row[l+64]),  c1), 0.f);
        float s2 = fmaxf(fmaf(a2, bf2f(row[l+128]), c2), 0.f);
        float s3 = fmaxf(fmaf(a3, bf2f(row[l+192]), c3), 0.f);
        float n2 = s0*s0 + s1*s1 + s2*s2 + s3*s3;
        #pragma unroll
        for (int off = 32; off; off >>= 1) n2 += __shfl_xor(n2, off, 64);
        float rn = 1.0f / fmaxf(sqrtf(n2), 1e-12f);
        float q0 = s0*rn, q1 = s1*rn, q2 = s2*rn, q3 = s3*rn;
        row[l]     = f2bf(q0);
        row[l+64]  = f2bf(q1);
        row[l+128] = f2bf(q2);
        row[l+192] = f2bf(q3);
        int base = gt[p]*COUT + l;
        atomicAdd(&lsum[base],     q0); atomicAdd(&lsq[base],     q0*q0);
        atomicAdd(&lsum[base+64],  q1); atomicAdd(&lsq[base+64],  q1*q1);
        atomicAdd(&lsum[base+128], q2); atomicAdd(&lsq[base+128], q2*q2);
        atomicAdd(&lsum[base+192], q3); atomicAdd(&lsq[base+192], q3*q3);
    }
    __syncthreads();
    float* gs = gsum_s   + (size_t)b*NCLS*COUT;
    float* gq = gsumsq_s + (size_t)b*NCLS*COUT;
    for (int i = t; i < NCLS*COUT; i += 512){
        atomicAdd(&gs[i], lsum[i]);
        atomicAdd(&gq[i], lsq[i]);
    }
}

// ---------- K4b: t l2norm + mse vs s_bar + class stats (t) ----------
__global__ __launch_bounds__(512) void k4b(const float* __restrict__ T, const u16* __restrict__ SX,
                                           const int* __restrict__ gt,
                                           float* __restrict__ gsum_t, float* __restrict__ gsumsq_t,
                                           float* __restrict__ msep){
    __shared__ float lsum[NCLS*COUT];
    __shared__ float lsq [NCLS*COUT];
    __shared__ float ts[COUT*65];
    __shared__ float msw[8];
    const int t = threadIdx.x, wid = t >> 6, l = t & 63;
    const int b  = blockIdx.x >> 5;
    const int pb = (blockIdx.x & 31) * 512;
    for (int i = t; i < NCLS*COUT; i += 512){ lsum[i] = 0.f; lsq[i] = 0.f; }
    const float* Tb = T + (size_t)b * COUT * NPIX;
    float msea = 0.f;
    __syncthreads();
    for (int tile = 0; tile < 8; tile++){
        const int q0 = pb + tile*64;
        __syncthreads();                    // protect ts from previous tile's readers
        #pragma unroll
        for (int it = 0; it < 8; it++){     // stage 256c x 64p fp32 tile
            int f = it*512 + t;
            int c = f >> 4, p4 = f & 15;
            float4 v = *reinterpret_cast<const float4*>(Tb + (size_t)c*NPIX + q0 + p4*4);
            float* d = &ts[c*65 + p4*4];
            d[0]=v.x; d[1]=v.y; d[2]=v.z; d[3]=v.w;
        }
        __syncthreads();
        #pragma unroll 2
        for (int u = 0; u < 8; u++){
            int pp = wid*8 + u;
            size_t p = (size_t)b*NPIX + q0 + pp;
            float t0 = ts[(l      )*65 + pp];
            float t1 = ts[(l + 64 )*65 + pp];
            float t2 = ts[(l + 128)*65 + pp];
            float t3 = ts[(l + 192)*65 + pp];
            float n2 = t0*t0 + t1*t1 + t2*t2 + t3*t3;
            #pragma unroll
            for (int off = 32; off; off >>= 1) n2 += __shfl_xor(n2, off, 64);
            float rn = 1.0f / fmaxf(sqrtf(n2), 1e-12f);
            t0 *= rn; t1 *= rn; t2 *= rn; t3 *= rn;
            const u16* srow = SX + p * SROW;
            float d0 = bf2f(srow[l])     - t0;
            float d1 = bf2f(srow[l+64])  - t1;
            float d2 = bf2f(srow[l+128]) - t2;
            float d3 = bf2f(srow[l+192]) - t3;
            msea += d0*d0 + d1*d1 + d2*d2 + d3*d3;
            int base = gt[p]*COUT + l;
            atomicAdd(&lsum[base],     t0); atomicAdd(&lsq[base],     t0*t0);
            atomicAdd(&lsum[base+64],  t1); atomicAdd(&lsq[base+64],  t1*t1);
            atomicAdd(&lsum[base+128], t2); atomicAdd(&lsq[base+128], t2*t2);
            atomicAdd(&lsum[base+192], t3); atomicAdd(&lsq[base+192], t3*t3);
        }
    }
    __syncthreads();
    float* gs = gsum_t   + (size_t)b*NCLS*COUT;
    float* gq = gsumsq_t + (size_t)b*NCLS*COUT;
    for (int i = t; i < NCLS*COUT; i += 512){
        atomicAdd(&gs[i], lsum[i]);
        atomicAdd(&gq[i], lsq[i]);
    }
    #pragma unroll
    for (int off = 32; off; off >>= 1) msea += __shfl_xor(msea, off, 64);
    if (l == 0) msw[wid] = msea;
    __syncthreads();
    if (t == 0){
        float v = 0.f;
        #pragma unroll
        for (int i = 0; i < 8; i++) v += msw[i];
        atomicAdd(msep, v);
    }
}

// ---------- K5: final scalar loss (wave-parallel, no in-loop barriers) ----------
__global__ void k5_final(const float* __restrict__ counts,
                         const float* __restrict__ gs,  const float* __restrict__ gqs,
                         const float* __restrict__ gtm, const float* __restrict__ gqt,
                         const float* __restrict__ msep, float* __restrict__ out){
    __shared__ float accm[4], accc[4];
    const int t = threadIdx.x, wid = t >> 6, l = t & 63;
    float am = 0.f, ac = 0.f;
    for (int i = 0; i < 42; i++){
        int bk = wid*42 + i;                 // 168 = 4 waves * 42
        float cnt = counts[bk];
        int k = bk % NCLS;
        float cs = fmaxf(cnt, 1.f);
        float dn = fmaxf(cnt - 1.f, 1.f);
        float a1 = 0.f, a2 = 0.f;
        #pragma unroll
        for (int q = 0; q < 4; q++){
            int idx = bk*COUT + l + q*64;
            float mus = gs[idx] / cs;
            float vas = (gqs[idx] - cnt*mus*mus) / dn + 1e-6f;
            float mut = gtm[idx] / cs;
            float vat = (gqt[idx] - cnt*mut*mut) / dn + 1e-6f;
            float dm = mus - mut, dv = vas - vat;
            a1 += dm*dm; a2 += dv*dv;
        }
        #pragma unroll
        for (int off = 32; off; off >>= 1){ a1 += __shfl_xor(a1, off, 64); a2 += __shfl_xor(a2, off, 64); }
        if (l == 0 && cnt > 1.f && k != 0){
            am += 0.5f * (a1 + a2) / (float)COUT;
            ac += 1.f;
        }
    }
    if (l == 0){ accm[wid] = am; accc[wid] = ac; }
    __syncthreads();
    if (t == 0){
        float L = accm[0]+accm[1]+accm[2]+accm[3];
        float N = accc[0]+accc[1]+accc[2]+accc[3];
        out[0] = L / (N + 1e-7f) + 0.5f * (msep[0] / (float)(MTOT * COUT));
    }
}

extern "C" void kernel_launch(void* const* d_in, const int* in_sizes, int n_in,
                              void* d_out, int out_size, void* d_ws, size_t ws_size,
                              hipStream_t stream){
    (void)in_sizes; (void)n_in; (void)out_size; (void)ws_size;
    const float* s_feat = (const float*)d_in[0];
    const float* t_feat = (const float*)d_in[1];
    const int*   gt     = (const int*)d_in[2];
    const float* Wp     = (const float*)d_in[3];
    const float* gamma  = (const float*)d_in[4];
    const float* beta   = (const float*)d_in[5];
    char* ws = (char*)d_ws;

    // workspace: SX (transposed s / x / s_bar) 83,886,080 | Wbf 163,840 | stats
    u16*   SX   = (u16*)ws;
    u16*   Wbf  = (u16*)(ws + 83886080);
    char*  z0   = ws + 84049920;
    float* bnsum    = (float*)(z0);
    float* bnsumsq  = (float*)(z0 + 1024);
    float* gsum_s   = (float*)(z0 + 2048);
    float* gsumsq_s = (float*)(z0 + 2048 + 172032);
    float* gsum_t   = (float*)(z0 + 2048 + 2*172032);
    float* gsumsq_t = (float*)(z0 + 2048 + 3*172032);
    float* msep     = (float*)(z0 + 690176);
    float* bna      = (float*)(z0 + 690240);
    float* bnb      = (float*)(z0 + 691264);
    float* counts   = (float*)(z0 + 692288);

    (void)hipMemsetAsync(z0, 0, 690240, stream);

    k0_wcvt  <<<80,    256, 0, stream>>>(Wp, Wbf);
    kt_strans<<<10240, 256, 0, stream>>>(s_feat, SX);
    k1_mfma  <<<1024,  256, 0, stream>>>(SX, Wbf, bnsum, bnsumsq);
    k2_bn    <<<1,     256, 0, stream>>>(bnsum, bnsumsq, gamma, beta, bna, bnb);
    k3_counts<<<8,     256, 0, stream>>>(gt, counts);
    k4a      <<<256,   512, 0, stream>>>(SX, gt, bna, bnb, gsum_s, gsumsq_s);
    k4b      <<<256,   512, 0, stream>>>(t_feat, SX, gt, gsum_t, gsumsq_t, msep);
    k5_final <<<1,     256, 0, stream>>>(counts, gsum_s, gsumsq_s, gsum_t, gsumsq_t, msep, (float*)d_out);
}

// Round 4
// 1037.517 us; speedup vs baseline: 1.0290x; 1.0290x over previous
//
#include <hip/hip_runtime.h>

typedef unsigned short u16;
typedef __attribute__((ext_vector_type(4))) float          f32x4;
typedef __attribute__((ext_vector_type(8))) short          bf8;
typedef __attribute__((ext_vector_type(8))) unsigned short us8;
typedef __attribute__((ext_vector_type(4))) unsigned short us4;

#define BATCH 8
#define CIN   320
#define COUT  256
#define NPIX  16384
#define NCLS  21
#define MTOT  (BATCH*NPIX)   // 131072
#define SROW  320            // u16 elements per SX row (s^T, later x in first 256)

__device__ __forceinline__ float bf2f(u16 v){
    unsigned int u = ((unsigned int)v) << 16;
    float f; __builtin_memcpy(&f, &u, 4); return f;
}
__device__ __forceinline__ u16 f2bf(float f){
    unsigned int u; __builtin_memcpy(&u, &f, 4);
    u += 0x7fffu + ((u >> 16) & 1u);
    return (u16)(u >> 16);
}

// ---------- K0: W fp32 [256][320] -> bf16 same layout ----------
__global__ void k0_wcvt(const float* __restrict__ W, u16* __restrict__ Wbf){
    int i4 = blockIdx.x * 256 + threadIdx.x;   // 20480 float4s exactly
    float4 v = reinterpret_cast<const float4*>(W)[i4];
    us4 o;
    o[0] = f2bf(v.x); o[1] = f2bf(v.y); o[2] = f2bf(v.z); o[3] = f2bf(v.w);
    reinterpret_cast<us4*>(Wbf)[i4] = o;
}

// ---------- KT: s_feat fp32 [b][320][P] -> SX bf16 [b*P][SROW] (transposed) ----------
__global__ __launch_bounds__(256) void kt_strans(const float* __restrict__ in, u16* __restrict__ out){
    __shared__ float tile[64*65];
    const int t  = threadIdx.x;
    const int bid = blockIdx.x;
    const int pt = bid & 255;          // 256 p-tiles of 64
    const int ct = (bid >> 8) % 5;     // 5 c-tiles of 64
    const int b  = bid / (256*5);
    const float* src = in + ((size_t)b*CIN + ct*64)*NPIX + pt*64;
    #pragma unroll
    for (int it = 0; it < 4; it++){
        int f = it*256 + t;
        int i = f >> 4, c4 = f & 15;
        float4 v = *reinterpret_cast<const float4*>(src + (size_t)i*NPIX + c4*4);
        float* d = &tile[i*65 + c4*4];
        d[0]=v.x; d[1]=v.y; d[2]=v.z; d[3]=v.w;
    }
    __syncthreads();
    u16* dst = out + ((size_t)(b*NPIX + pt*64))*SROW + ct*64;
    #pragma unroll
    for (int it = 0; it < 2; it++){
        int f = it*256 + t;
        int p = f >> 3, c8 = f & 7;
        us8 o;
        #pragma unroll
        for (int j = 0; j < 8; j++) o[j] = f2bf(tile[(c8*8+j)*65 + p]);
        *reinterpret_cast<us8*>(dst + (size_t)p*SROW + c8*8) = o;
    }
}

// ---------- K1: MFMA GEMM x[p][o] = sum_c SX[p][c]*W[o][c]; writes x bf16 in place; BN sums ----------
__global__ __launch_bounds__(256) void k1_mfma(u16* SX, const u16* __restrict__ Wbf,
                                               float* __restrict__ bnsum, float* __restrict__ bnsumsq){
    __shared__ __align__(16) char sm[67584];   // K-loop: Sa[128 rows][128B swizzled]; epilogue: Xs[128][264] bf16
    __shared__ float bns[512];
    const int t = threadIdx.x;
    const int wid = t >> 6, l = t & 63;
    const size_t pblk = (size_t)blockIdx.x * 128;
    const int wm = (wid & 1) * 64;     // m (pixel) offset of wave
    const int wn = (wid >> 1) * 128;   // n (channel) offset of wave
    bns[t] = 0.f; bns[t+256] = 0.f;

    f32x4 acc[4][8];
    #pragma unroll
    for (int mi = 0; mi < 4; mi++)
        #pragma unroll
        for (int ni = 0; ni < 8; ni++)
            acc[mi][ni] = (f32x4){0.f,0.f,0.f,0.f};

    // staging: thread -> (row sp(+32*it), 16B chunk sg)
    const int sg = t & 7, sp = t >> 3;
    const u16* srcb = SX + (pblk + sp) * SROW + sg * 8;
    us8 stg[4];
    #pragma unroll
    for (int it = 0; it < 4; it++)
        stg[it] = *reinterpret_cast<const us8*>(srcb + (size_t)it*32*SROW);

    for (int kt = 0; kt < 5; kt++){
        __syncthreads();                       // LDS free (prev compute done)
        #pragma unroll
        for (int it = 0; it < 4; it++){        // regs -> swizzled LDS
            int p = sp + it*32;
            int byt = p*128 + ((sg*16) ^ ((p&7)<<4));
            *reinterpret_cast<us8*>(&sm[byt]) = stg[it];
        }
        if (kt < 4){                           // prefetch next K-tile (overlaps compute)
            #pragma unroll
            for (int it = 0; it < 4; it++)
                stg[it] = *reinterpret_cast<const us8*>(srcb + (size_t)it*32*SROW + (kt+1)*64);
        }
        __syncthreads();                       // tile ready
        #pragma unroll
        for (int ks = 0; ks < 2; ks++){
            bf8 bfr[8], afr[4];
            const u16* wp = Wbf + (size_t)(wn + (l & 15)) * CIN + kt*64 + ks*32 + (l >> 4)*8;
            #pragma unroll
            for (int ni = 0; ni < 8; ni++)
                bfr[ni] = *reinterpret_cast<const bf8*>(wp + (size_t)ni*16*CIN);
            #pragma unroll
            for (int mi = 0; mi < 4; mi++){
                int p = wm + mi*16 + (l & 15);
                int byt = p*128 + (((ks*4 + (l>>4))*16) ^ ((p&7)<<4));
                afr[mi] = *reinterpret_cast<const bf8*>(&sm[byt]);
            }
            #pragma unroll
            for (int mi = 0; mi < 4; mi++)
                #pragma unroll
                for (int ni = 0; ni < 8; ni++)
                    acc[mi][ni] = __builtin_amdgcn_mfma_f32_16x16x32_bf16(afr[mi], bfr[ni], acc[mi][ni], 0, 0, 0);
        }
    }
    __syncthreads();
    // acc -> Xs [128][264] bf16
    #pragma unroll
    for (int mi = 0; mi < 4; mi++)
        #pragma unroll
        for (int ni = 0; ni < 8; ni++)
            #pragma unroll
            for (int r = 0; r < 4; r++){
                int p = wm + mi*16 + (l>>4)*4 + r;
                int o = wn + ni*16 + (l&15);
                *reinterpret_cast<u16*>(&sm[(p*264 + o)*2]) = f2bf(acc[mi][ni][r]);
            }
    __syncthreads();
    // coalesced readback -> global (in place over SX rows, stride SROW) + BN partial sums
    float s1[8], s2[8];
    #pragma unroll
    for (int j = 0; j < 8; j++){ s1[j] = 0.f; s2[j] = 0.f; }
    const int oc = (t & 31) * 8;
    const int pr = t >> 5;
    #pragma unroll
    for (int it = 0; it < 16; it++){
        int p = pr + it*8;
        us8 v = *reinterpret_cast<const us8*>(&sm[(p*264 + oc)*2]);
        *reinterpret_cast<us8*>(SX + (pblk + p)*SROW + oc) = v;
        #pragma unroll
        for (int j = 0; j < 8; j++){
            float fv = bf2f(v[j]);
            s1[j] += fv; s2[j] += fv*fv;
        }
    }
    #pragma unroll
    for (int j = 0; j < 8; j++){
        atomicAdd(&bns[oc + j],       s1[j]);
        atomicAdd(&bns[256 + oc + j], s2[j]);
    }
    __syncthreads();
    atomicAdd(&bnsum[t],   bns[t]);
    atomicAdd(&bnsumsq[t], bns[t + 256]);
}

// ---------- K2: BN affine coefficients ----------
__global__ void k2_bn(const float* __restrict__ bnsum, const float* __restrict__ bnsumsq,
                      const float* __restrict__ gamma, const float* __restrict__ beta,
                      float* __restrict__ bna, float* __restrict__ bnb){
    int o = threadIdx.x;
    float m = bnsum[o] / (float)MTOT;
    float v = bnsumsq[o] / (float)MTOT - m * m;
    float a = gamma[o] / sqrtf(v + 1e-5f);
    bna[o] = a;
    bnb[o] = beta[o] - m * a;
}

// ---------- K3: per-batch class histogram (256 blocks, global atomic merge) ----------
__global__ void k3_counts(const int* __restrict__ gt, float* __restrict__ counts){
    __shared__ float h[NCLS];
    const int b = blockIdx.x >> 5, seg = blockIdx.x & 31, t = threadIdx.x;
    if (t < NCLS) h[t] = 0.f;
    __syncthreads();
    const int* g = gt + b * NPIX + seg * 512;
    for (int i = t; i < 512; i += 256) atomicAdd(&h[g[i]], 1.0f);
    __syncthreads();
    if (t < NCLS) atomicAdd(&counts[b * NCLS + t], h[t]);
}

// ---------- K4: fused BN+ReLU+norm(s) + norm(t) + mse + both class stats ----------
__global__ __launch_bounds__(1024) void k4_fused(const u16* __restrict__ SX, const float* __restrict__ T,
                                                 const int* __restrict__ gt,
                                                 const float* __restrict__ bna, const float* __restrict__ bnb,
                                                 float* __restrict__ gss, float* __restrict__ gsq,
                                                 float* __restrict__ gts, float* __restrict__ gtq,
                                                 float* __restrict__ msep){
    __shared__ float lss[NCLS*COUT];
    __shared__ float lsq[NCLS*COUT];
    __shared__ float lts[NCLS*COUT];
    __shared__ float ltq[NCLS*COUT];
    __shared__ float ts[COUT][65];       // 64-px fp32 t tile (transposed in LDS)
    __shared__ float msw[16];
    const int t = threadIdx.x, wid = t >> 6, l = t & 63;
    const int b  = blockIdx.x >> 5;              // 32 blocks per batch
    const int pb = (blockIdx.x & 31) * 512;      // 512 px per block
    for (int i = t; i < NCLS*COUT; i += 1024){ lss[i]=0.f; lsq[i]=0.f; lts[i]=0.f; ltq[i]=0.f; }
    const float a0=bna[l],     a1=bna[l+64],  a2=bna[l+128], a3=bna[l+192];
    const float c0=bnb[l],     c1=bnb[l+64],  c2=bnb[l+128], c3=bnb[l+192];
    const float* Tb = T + (size_t)b * COUT * NPIX;
    const int* gtb = gt + b * NPIX;
    const u16* Xb = SX + (size_t)b * NPIX * SROW;
    float msea = 0.f;
    __syncthreads();

    for (int tile = 0; tile < 8; tile++){
        const int q0 = pb + tile*64;
        __syncthreads();                          // previous tile fully consumed
        #pragma unroll
        for (int it = 0; it < 4; it++){           // stage 256c x 64p fp32 (coalesced float4)
            int f = it*1024 + t;
            int c = f >> 4, p4 = f & 15;
            float4 v = *reinterpret_cast<const float4*>(Tb + (size_t)c*NPIX + q0 + p4*4);
            float* d = &ts[c][p4*4];
            d[0]=v.x; d[1]=v.y; d[2]=v.z; d[3]=v.w;
        }
        __syncthreads();
        #pragma unroll
        for (int u = 0; u < 4; u++){              // 4 pixels per wave per tile
            const int pp = wid*4 + u;
            const int p  = q0 + pp;
            const u16* xr = Xb + (size_t)p * SROW;
            float x0 = bf2f(xr[l]), x1 = bf2f(xr[l+64]), x2 = bf2f(xr[l+128]), x3 = bf2f(xr[l+192]);
            float s0 = fmaxf(fmaf(a0,x0,c0),0.f), s1 = fmaxf(fmaf(a1,x1,c1),0.f);
            float s2 = fmaxf(fmaf(a2,x2,c2),0.f), s3 = fmaxf(fmaf(a3,x3,c3),0.f);
            float t0 = ts[l][pp], t1 = ts[l+64][pp], t2 = ts[l+128][pp], t3 = ts[l+192][pp];
            float ns = s0*s0 + s1*s1 + s2*s2 + s3*s3;
            float nt = t0*t0 + t1*t1 + t2*t2 + t3*t3;
            #pragma unroll
            for (int off = 32; off; off >>= 1){
                ns += __shfl_xor(ns, off, 64);
                nt += __shfl_xor(nt, off, 64);
            }
            float rs = 1.0f / fmaxf(sqrtf(ns), 1e-12f);
            float rt = 1.0f / fmaxf(sqrtf(nt), 1e-12f);
            s0 *= rs; s1 *= rs; s2 *= rs; s3 *= rs;
            t0 *= rt; t1 *= rt; t2 *= rt; t3 *= rt;
            float d0 = s0-t0, d1 = s1-t1, d2 = s2-t2, d3 = s3-t3;
            msea += d0*d0 + d1*d1 + d2*d2 + d3*d3;
            const int base = gtb[p]*COUT + l;
            atomicAdd(&lss[base],     s0); atomicAdd(&lsq[base],     s0*s0);
            atomicAdd(&lss[base+64],  s1); atomicAdd(&lsq[base+64],  s1*s1);
            atomicAdd(&lss[base+128], s2); atomicAdd(&lsq[base+128], s2*s2);
            atomicAdd(&lss[base+192], s3); atomicAdd(&lsq[base+192], s3*s3);
            atomicAdd(&lts[base],     t0); atomicAdd(&ltq[base],     t0*t0);
            atomicAdd(&lts[base+64],  t1); atomicAdd(&ltq[base+64],  t1*t1);
            atomicAdd(&lts[base+128], t2); atomicAdd(&ltq[base+128], t2*t2);
            atomicAdd(&lts[base+192], t3); atomicAdd(&ltq[base+192], t3*t3);
        }
    }
    __syncthreads();
    float* GS  = gss + (size_t)b*NCLS*COUT;
    float* GQ  = gsq + (size_t)b*NCLS*COUT;
    float* GTS = gts + (size_t)b*NCLS*COUT;
    float* GTQ = gtq + (size_t)b*NCLS*COUT;
    for (int i = t; i < NCLS*COUT; i += 1024){
        atomicAdd(&GS[i],  lss[i]);
        atomicAdd(&GQ[i],  lsq[i]);
        atomicAdd(&GTS[i], lts[i]);
        atomicAdd(&GTQ[i], ltq[i]);
    }
    #pragma unroll
    for (int off = 32; off; off >>= 1) msea += __shfl_xor(msea, off, 64);
    if (l == 0) msw[wid] = msea;
    __syncthreads();
    if (t == 0){
        float v = 0.f;
        #pragma unroll
        for (int i = 0; i < 16; i++) v += msw[i];
        atomicAdd(msep, v);
    }
}

// ---------- K5: final scalar loss (wave-parallel, no in-loop barriers) ----------
__global__ void k5_final(const float* __restrict__ counts,
                         const float* __restrict__ gs,  const float* __restrict__ gqs,
                         const float* __restrict__ gtm, const float* __restrict__ gqt,
                         const float* __restrict__ msep, float* __restrict__ out){
    __shared__ float accm[4], accc[4];
    const int t = threadIdx.x, wid = t >> 6, l = t & 63;
    float am = 0.f, ac = 0.f;
    for (int i = 0; i < 42; i++){
        int bk = wid*42 + i;                 // 168 = 4 waves * 42
        float cnt = counts[bk];
        int k = bk % NCLS;
        float cs = fmaxf(cnt, 1.f);
        float dn = fmaxf(cnt - 1.f, 1.f);
        float a1 = 0.f, a2 = 0.f;
        #pragma unroll
        for (int q = 0; q < 4; q++){
            int idx = bk*COUT + l + q*64;
            float mus = gs[idx] / cs;
            float vas = (gqs[idx] - cnt*mus*mus) / dn + 1e-6f;
            float mut = gtm[idx] / cs;
            float vat = (gqt[idx] - cnt*mut*mut) / dn + 1e-6f;
            float dm = mus - mut, dv = vas - vat;
            a1 += dm*dm; a2 += dv*dv;
        }
        #pragma unroll
        for (int off = 32; off; off >>= 1){ a1 += __shfl_xor(a1, off, 64); a2 += __shfl_xor(a2, off, 64); }
        if (l == 0 && cnt > 1.f && k != 0){
            am += 0.5f * (a1 + a2) / (float)COUT;
            ac += 1.f;
        }
    }
    if (l == 0){ accm[wid] = am; accc[wid] = ac; }
    __syncthreads();
    if (t == 0){
        float L = accm[0]+accm[1]+accm[2]+accm[3];
        float N = accc[0]+accc[1]+accc[2]+accc[3];
        out[0] = L / (N + 1e-7f) + 0.5f * (msep[0] / (float)(MTOT * COUT));
    }
}

extern "C" void kernel_launch(void* const* d_in, const int* in_sizes, int n_in,
                              void* d_out, int out_size, void* d_ws, size_t ws_size,
                              hipStream_t stream){
    (void)in_sizes; (void)n_in; (void)out_size; (void)ws_size;
    const float* s_feat = (const float*)d_in[0];
    const float* t_feat = (const float*)d_in[1];
    const int*   gt     = (const int*)d_in[2];
    const float* Wp     = (const float*)d_in[3];
    const float* gamma  = (const float*)d_in[4];
    const float* beta   = (const float*)d_in[5];
    char* ws = (char*)d_ws;

    // workspace: SX (transposed s -> x) 83,886,080 | Wbf 163,840 | stats
    u16*   SX   = (u16*)ws;
    u16*   Wbf  = (u16*)(ws + 83886080);
    char*  z0   = ws + 84049920;
    float* bnsum    = (float*)(z0);
    float* bnsumsq  = (float*)(z0 + 1024);
    float* gsum_s   = (float*)(z0 + 2048);
    float* gsumsq_s = (float*)(z0 + 2048 + 172032);
    float* gsum_t   = (float*)(z0 + 2048 + 2*172032);
    float* gsumsq_t = (float*)(z0 + 2048 + 3*172032);
    float* msep     = (float*)(z0 + 690176);
    float* bna      = (float*)(z0 + 690240);
    float* bnb      = (float*)(z0 + 691264);
    float* counts   = (float*)(z0 + 692288);

    (void)hipMemsetAsync(z0, 0, 692960, stream);   // all sums/stats/mse/counts

    k0_wcvt  <<<80,    256,  0, stream>>>(Wp, Wbf);
    kt_strans<<<10240, 256,  0, stream>>>(s_feat, SX);
    k1_mfma  <<<1024,  256,  0, stream>>>(SX, Wbf, bnsum, bnsumsq);
    k2_bn    <<<1,     256,  0, stream>>>(bnsum, bnsumsq, gamma, beta, bna, bnb);
    k3_counts<<<256,   256,  0, stream>>>(gt, counts);
    k4_fused <<<256,   1024, 0, stream>>>(SX, t_feat, gt, bna, bnb,
                                          gsum_s, gsumsq_s, gsum_t, gsumsq_t, msep);
    k5_final <<<1,     256,  0, stream>>>(counts, gsum_s, gsumsq_s, gsum_t, gsumsq_t, msep, (float*)d_out);
}

// Round 5
// 538.847 us; speedup vs baseline: 1.9812x; 1.9254x over previous
//
#include <hip/hip_runtime.h>

typedef unsigned short u16;
typedef __attribute__((ext_vector_type(4))) float          f32x4;
typedef __attribute__((ext_vector_type(8))) short          bf8;
typedef __attribute__((ext_vector_type(8))) unsigned short us8;
typedef __attribute__((ext_vector_type(4))) unsigned short us4;

#define BATCH 8
#define CIN   320
#define COUT  256
#define NPIX  16384
#define NCLS  21
#define KCLS  32             // padded class rows for MFMA (rows 21..31 stay zero)
#define MTOT  (BATCH*NPIX)   // 131072
#define SROW  320            // u16 elements per SX row (s^T, later x in first 256)

__device__ __forceinline__ float bf2f(u16 v){
    unsigned int u = ((unsigned int)v) << 16;
    float f; __builtin_memcpy(&f, &u, 4); return f;
}
__device__ __forceinline__ u16 f2bf(float f){
    unsigned int u; __builtin_memcpy(&u, &f, 4);
    u += 0x7fffu + ((u >> 16) & 1u);
    return (u16)(u >> 16);
}

// swizzled u16 index into a [64px][256c] bf16 LDS tile.
// XOR of px-bits 3..4 into c-bits 4..5 -> conflict-free row writes AND
// conflict-free strided fragment reads (8 px, fixed c).
__device__ __forceinline__ int swz_idx(int px, int c){
    return px * 256 + (c ^ (((px >> 3) & 3) << 4));
}

// ---------- K0: W fp32 [256][320] -> bf16 same layout ----------
__global__ void k0_wcvt(const float* __restrict__ W, u16* __restrict__ Wbf){
    int i4 = blockIdx.x * 256 + threadIdx.x;   // 20480 float4s exactly
    float4 v = reinterpret_cast<const float4*>(W)[i4];
    us4 o;
    o[0] = f2bf(v.x); o[1] = f2bf(v.y); o[2] = f2bf(v.z); o[3] = f2bf(v.w);
    reinterpret_cast<us4*>(Wbf)[i4] = o;
}

// ---------- KT: s_feat fp32 [b][320][P] -> SX bf16 [b*P][SROW] (transposed) ----------
__global__ __launch_bounds__(256) void kt_strans(const float* __restrict__ in, u16* __restrict__ out){
    __shared__ float tile[64*65];
    const int t  = threadIdx.x;
    const int bid = blockIdx.x;
    const int pt = bid & 255;          // 256 p-tiles of 64
    const int ct = (bid >> 8) % 5;     // 5 c-tiles of 64
    const int b  = bid / (256*5);
    const float* src = in + ((size_t)b*CIN + ct*64)*NPIX + pt*64;
    #pragma unroll
    for (int it = 0; it < 4; it++){
        int f = it*256 + t;
        int i = f >> 4, c4 = f & 15;
        float4 v = *reinterpret_cast<const float4*>(src + (size_t)i*NPIX + c4*4);
        float* d = &tile[i*65 + c4*4];
        d[0]=v.x; d[1]=v.y; d[2]=v.z; d[3]=v.w;
    }
    __syncthreads();
    u16* dst = out + ((size_t)(b*NPIX + pt*64))*SROW + ct*64;
    #pragma unroll
    for (int it = 0; it < 2; it++){
        int f = it*256 + t;
        int p = f >> 3, c8 = f & 7;
        us8 o;
        #pragma unroll
        for (int j = 0; j < 8; j++) o[j] = f2bf(tile[(c8*8+j)*65 + p]);
        *reinterpret_cast<us8*>(dst + (size_t)p*SROW + c8*8) = o;
    }
}

// ---------- K1: MFMA GEMM x[p][o] = sum_c SX[p][c]*W[o][c]; writes x bf16 in place; BN sums ----------
__global__ __launch_bounds__(256) void k1_mfma(u16* SX, const u16* __restrict__ Wbf,
                                               float* __restrict__ bnsum, float* __restrict__ bnsumsq){
    __shared__ __align__(16) char sm[67584];
    __shared__ float bns[512];
    const int t = threadIdx.x;
    const int wid = t >> 6, l = t & 63;
    const size_t pblk = (size_t)blockIdx.x * 128;
    const int wm = (wid & 1) * 64;
    const int wn = (wid >> 1) * 128;
    bns[t] = 0.f; bns[t+256] = 0.f;

    f32x4 acc[4][8];
    #pragma unroll
    for (int mi = 0; mi < 4; mi++)
        #pragma unroll
        for (int ni = 0; ni < 8; ni++)
            acc[mi][ni] = (f32x4){0.f,0.f,0.f,0.f};

    const int sg = t & 7, sp = t >> 3;
    const u16* srcb = SX + (pblk + sp) * SROW + sg * 8;
    us8 stg[4];
    #pragma unroll
    for (int it = 0; it < 4; it++)
        stg[it] = *reinterpret_cast<const us8*>(srcb + (size_t)it*32*SROW);

    for (int kt = 0; kt < 5; kt++){
        __syncthreads();
        #pragma unroll
        for (int it = 0; it < 4; it++){
            int p = sp + it*32;
            int byt = p*128 + ((sg*16) ^ ((p&7)<<4));
            *reinterpret_cast<us8*>(&sm[byt]) = stg[it];
        }
        if (kt < 4){
            #pragma unroll
            for (int it = 0; it < 4; it++)
                stg[it] = *reinterpret_cast<const us8*>(srcb + (size_t)it*32*SROW + (kt+1)*64);
        }
        __syncthreads();
        #pragma unroll
        for (int ks = 0; ks < 2; ks++){
            bf8 bfr[8], afr[4];
            const u16* wp = Wbf + (size_t)(wn + (l & 15)) * CIN + kt*64 + ks*32 + (l >> 4)*8;
            #pragma unroll
            for (int ni = 0; ni < 8; ni++)
                bfr[ni] = *reinterpret_cast<const bf8*>(wp + (size_t)ni*16*CIN);
            #pragma unroll
            for (int mi = 0; mi < 4; mi++){
                int p = wm + mi*16 + (l & 15);
                int byt = p*128 + (((ks*4 + (l>>4))*16) ^ ((p&7)<<4));
                afr[mi] = *reinterpret_cast<const bf8*>(&sm[byt]);
            }
            #pragma unroll
            for (int mi = 0; mi < 4; mi++)
                #pragma unroll
                for (int ni = 0; ni < 8; ni++)
                    acc[mi][ni] = __builtin_amdgcn_mfma_f32_16x16x32_bf16(afr[mi], bfr[ni], acc[mi][ni], 0, 0, 0);
        }
    }
    __syncthreads();
    #pragma unroll
    for (int mi = 0; mi < 4; mi++)
        #pragma unroll
        for (int ni = 0; ni < 8; ni++)
            #pragma unroll
            for (int r = 0; r < 4; r++){
                int p = wm + mi*16 + (l>>4)*4 + r;
                int o = wn + ni*16 + (l&15);
                *reinterpret_cast<u16*>(&sm[(p*264 + o)*2]) = f2bf(acc[mi][ni][r]);
            }
    __syncthreads();
    float s1[8], s2[8];
    #pragma unroll
    for (int j = 0; j < 8; j++){ s1[j] = 0.f; s2[j] = 0.f; }
    const int oc = (t & 31) * 8;
    const int pr = t >> 5;
    #pragma unroll
    for (int it = 0; it < 16; it++){
        int p = pr + it*8;
        us8 v = *reinterpret_cast<const us8*>(&sm[(p*264 + oc)*2]);
        *reinterpret_cast<us8*>(SX + (pblk + p)*SROW + oc) = v;
        #pragma unroll
        for (int j = 0; j < 8; j++){
            float fv = bf2f(v[j]);
            s1[j] += fv; s2[j] += fv*fv;
        }
    }
    #pragma unroll
    for (int j = 0; j < 8; j++){
        atomicAdd(&bns[oc + j],       s1[j]);
        atomicAdd(&bns[256 + oc + j], s2[j]);
    }
    __syncthreads();
    atomicAdd(&bnsum[t],   bns[t]);
    atomicAdd(&bnsumsq[t], bns[t + 256]);
}

// ---------- K2: BN affine coefficients ----------
__global__ void k2_bn(const float* __restrict__ bnsum, const float* __restrict__ bnsumsq,
                      const float* __restrict__ gamma, const float* __restrict__ beta,
                      float* __restrict__ bna, float* __restrict__ bnb){
    int o = threadIdx.x;
    float m = bnsum[o] / (float)MTOT;
    float v = bnsumsq[o] / (float)MTOT - m * m;
    float a = gamma[o] / sqrtf(v + 1e-5f);
    bna[o] = a;
    bnb[o] = beta[o] - m * a;
}

// ---------- K3: class histogram ----------
__global__ void k3_counts(const int* __restrict__ gt, float* __restrict__ counts){
    __shared__ float h[NCLS];
    const int b = blockIdx.x >> 5, seg = blockIdx.x & 31, t = threadIdx.x;
    if (t < NCLS) h[t] = 0.f;
    __syncthreads();
    const int* g = gt + b * NPIX + seg * 512;
    for (int i = t; i < 512; i += 256) atomicAdd(&h[g[i]], 1.0f);
    __syncthreads();
    if (t < NCLS) atomicAdd(&counts[b * NCLS + t], h[t]);
}

// ---------- K4: fused norm(s,t) + mse + class stats via one-hot MFMA (NO LDS atomics) ----------
__global__ __launch_bounds__(1024) void k4_fused(const u16* __restrict__ SX, const float* __restrict__ T,
                                                 const int* __restrict__ gt,
                                                 const float* __restrict__ bna, const float* __restrict__ bnb,
                                                 float* __restrict__ gss, float* __restrict__ gsq,
                                                 float* __restrict__ gts, float* __restrict__ gtq,
                                                 float* __restrict__ msep){
    __shared__ float ts[COUT][65];     // raw t tile (f32), [c][px]
    __shared__ u16 sb[64*256];         // s_bar bf16 tile, [px][c] swizzled
    __shared__ u16 tb[64*256];         // t_bar bf16 tile
    __shared__ int gtile[64];
    __shared__ float msw[16];
    const int t = threadIdx.x, wid = t >> 6, l = t & 63;
    const int b  = blockIdx.x >> 5;
    const int pb = (blockIdx.x & 31) * 512;
    const float a0=bna[l], a1=bna[l+64], a2=bna[l+128], a3=bna[l+192];
    const float c0=bnb[l], c1=bnb[l+64], c2=bnb[l+128], c3=bnb[l+192];
    const float* Tb = T + (size_t)b * COUT * NPIX;
    const int* gtb = gt + b * NPIX;
    const u16* Xb = SX + (size_t)b * NPIX * SROW;
    float msea = 0.f;

    // stats accumulators: [type: 0=s,1=s^2,2=t,3=t^2][mtile]
    f32x4 acc[4][2];
    #pragma unroll
    for (int ty = 0; ty < 4; ty++)
        #pragma unroll
        for (int mt = 0; mt < 2; mt++)
            acc[ty][mt] = (f32x4){0.f,0.f,0.f,0.f};

    // staging decomposition: thread -> (channel sc + 64*it, pixel quad sp4)
    const int sc = t >> 4, sp4 = t & 15;
    float4 stg[4];
    int gstg = 0;
    {   // prologue prefetch: tile 0
        #pragma unroll
        for (int it = 0; it < 4; it++)
            stg[it] = *reinterpret_cast<const float4*>(Tb + (size_t)(it*64 + sc)*NPIX + pb + sp4*4);
        if (t < 64) gstg = gtb[pb + t];
    }

    for (int tile = 0; tile < 8; tile++){
        const int q0 = pb + tile*64;
        // ---- commit staged t tile + gt tile ----
        #pragma unroll
        for (int it = 0; it < 4; it++){
            float4 v = stg[it];
            float* d = &ts[it*64 + sc][sp4*4];
            d[0]=v.x; d[1]=v.y; d[2]=v.z; d[3]=v.w;
        }
        if (t < 64) gtile[t] = gstg;
        __syncthreads();

        // ---- norm phase: 4 pixels per wave, lane owns channels l+64m ----
        {
            float sq[4][4], tq[4][4], ns[4], nt[4];
            #pragma unroll
            for (int u = 0; u < 4; u++){
                const int pp = wid*4 + u;
                const u16* xr = Xb + (size_t)(q0 + pp) * SROW;
                sq[u][0] = fmaxf(fmaf(a0, bf2f(xr[l]),     c0), 0.f);
                sq[u][1] = fmaxf(fmaf(a1, bf2f(xr[l+64]),  c1), 0.f);
                sq[u][2] = fmaxf(fmaf(a2, bf2f(xr[l+128]), c2), 0.f);
                sq[u][3] = fmaxf(fmaf(a3, bf2f(xr[l+192]), c3), 0.f);
                tq[u][0] = ts[l][pp];     tq[u][1] = ts[l+64][pp];
                tq[u][2] = ts[l+128][pp]; tq[u][3] = ts[l+192][pp];
                ns[u] = sq[u][0]*sq[u][0] + sq[u][1]*sq[u][1] + sq[u][2]*sq[u][2] + sq[u][3]*sq[u][3];
                nt[u] = tq[u][0]*tq[u][0] + tq[u][1]*tq[u][1] + tq[u][2]*tq[u][2] + tq[u][3]*tq[u][3];
            }
            #pragma unroll
            for (int off = 32; off; off >>= 1){
                #pragma unroll
                for (int u = 0; u < 4; u++){
                    ns[u] += __shfl_xor(ns[u], off, 64);
                    nt[u] += __shfl_xor(nt[u], off, 64);
                }
            }
            #pragma unroll
            for (int u = 0; u < 4; u++){
                const int pp = wid*4 + u;
                const int swz = ((pp >> 3) & 3) << 4;
                const int base = pp * 256;
                float rs = 1.0f / fmaxf(sqrtf(ns[u]), 1e-12f);
                float rt = 1.0f / fmaxf(sqrtf(nt[u]), 1e-12f);
                #pragma unroll
                for (int m = 0; m < 4; m++){
                    float sv = sq[u][m] * rs;
                    float tv = tq[u][m] * rt;
                    sb[base + ((l + 64*m) ^ swz)] = f2bf(sv);
                    tb[base + ((l + 64*m) ^ swz)] = f2bf(tv);
                    float d = sv - tv;
                    msea += d * d;
                }
            }
        }
        __syncthreads();

        // ---- prefetch next tile (overlaps MFMA) ----
        if (tile < 7){
            const int q1 = q0 + 64;
            #pragma unroll
            for (int it = 0; it < 4; it++)
                stg[it] = *reinterpret_cast<const float4*>(Tb + (size_t)(it*64 + sc)*NPIX + q1 + sp4*4);
            if (t < 64) gstg = gtb[q1 + t];
        }

        // ---- MFMA stats phase: wave owns 16-channel slice ----
        {
            const int cw = wid*16 + (l & 15);
            const int g  = l >> 4;
            #pragma unroll
            for (int ks = 0; ks < 2; ks++){
                int gv[8];
                #pragma unroll
                for (int j = 0; j < 8; j++) gv[j] = gtile[ks*32 + g*8 + j];
                bf8 bS, bT, bS2, bT2;
                #pragma unroll
                for (int j = 0; j < 8; j++){
                    int px = ks*32 + g*8 + j;
                    int idx = swz_idx(px, cw);
                    u16 vs = sb[idx], vt = tb[idx];
                    bS[j] = (short)vs; bT[j] = (short)vt;
                    float fs = bf2f(vs), ft = bf2f(vt);
                    bS2[j] = (short)f2bf(fs * fs);
                    bT2[j] = (short)f2bf(ft * ft);
                }
                bf8 aA0, aA1;
                #pragma unroll
                for (int j = 0; j < 8; j++){
                    aA0[j] = (short)((gv[j] == (l & 15))      ? 0x3F80 : 0);
                    aA1[j] = (short)((gv[j] == (l & 15) + 16) ? 0x3F80 : 0);
                }
                acc[0][0] = __builtin_amdgcn_mfma_f32_16x16x32_bf16(aA0, bS,  acc[0][0], 0,0,0);
                acc[0][1] = __builtin_amdgcn_mfma_f32_16x16x32_bf16(aA1, bS,  acc[0][1], 0,0,0);
                acc[1][0] = __builtin_amdgcn_mfma_f32_16x16x32_bf16(aA0, bS2, acc[1][0], 0,0,0);
                acc[1][1] = __builtin_amdgcn_mfma_f32_16x16x32_bf16(aA1, bS2, acc[1][1], 0,0,0);
                acc[2][0] = __builtin_amdgcn_mfma_f32_16x16x32_bf16(aA0, bT,  acc[2][0], 0,0,0);
                acc[2][1] = __builtin_amdgcn_mfma_f32_16x16x32_bf16(aA1, bT,  acc[2][1], 0,0,0);
                acc[3][0] = __builtin_amdgcn_mfma_f32_16x16x32_bf16(aA0, bT2, acc[3][0], 0,0,0);
                acc[3][1] = __builtin_amdgcn_mfma_f32_16x16x32_bf16(aA1, bT2, acc[3][1], 0,0,0);
            }
        }
        __syncthreads();
    }

    // ---- epilogue: stats -> global atomics (once per block) ----
    {
        const int cw = wid*16 + (l & 15);
        float* G[4] = { gss + (size_t)b*KCLS*COUT, gsq + (size_t)b*KCLS*COUT,
                        gts + (size_t)b*KCLS*COUT, gtq + (size_t)b*KCLS*COUT };
        #pragma unroll
        for (int ty = 0; ty < 4; ty++)
            #pragma unroll
            for (int mt = 0; mt < 2; mt++)
                #pragma unroll
                for (int r = 0; r < 4; r++){
                    int k = mt*16 + (l>>4)*4 + r;   // D row = class
                    atomicAdd(&G[ty][k*COUT + cw], acc[ty][mt][r]);
                }
    }
    // ---- mse reduce ----
    #pragma unroll
    for (int off = 32; off; off >>= 1) msea += __shfl_xor(msea, off, 64);
    if (l == 0) msw[wid] = msea;
    __syncthreads();
    if (t == 0){
        float v = 0.f;
        #pragma unroll
        for (int i = 0; i < 16; i++) v += msw[i];
        atomicAdd(msep, v);
    }
}

// ---------- K5: final scalar loss ----------
__global__ void k5_final(const float* __restrict__ counts,
                         const float* __restrict__ gs,  const float* __restrict__ gqs,
                         const float* __restrict__ gtm, const float* __restrict__ gqt,
                         const float* __restrict__ msep, float* __restrict__ out){
    __shared__ float accm[4], accc[4];
    const int t = threadIdx.x, wid = t >> 6, l = t & 63;
    float am = 0.f, ac = 0.f;
    for (int i = 0; i < 42; i++){
        int bk = wid*42 + i;                 // 168 = 4 waves * 42
        float cnt = counts[bk];
        int b = bk / NCLS, k = bk - b*NCLS;
        float cs = fmaxf(cnt, 1.f);
        float dn = fmaxf(cnt - 1.f, 1.f);
        float a1 = 0.f, a2 = 0.f;
        #pragma unroll
        for (int q = 0; q < 4; q++){
            int idx = (b*KCLS + k)*COUT + l + q*64;
            float mus = gs[idx] / cs;
            float vas = (gqs[idx] - cnt*mus*mus) / dn + 1e-6f;
            float mut = gtm[idx] / cs;
            float vat = (gqt[idx] - cnt*mut*mut) / dn + 1e-6f;
            float dm = mus - mut, dv = vas - vat;
            a1 += dm*dm; a2 += dv*dv;
        }
        #pragma unroll
        for (int off = 32; off; off >>= 1){ a1 += __shfl_xor(a1, off, 64); a2 += __shfl_xor(a2, off, 64); }
        if (l == 0 && cnt > 1.f && k != 0){
            am += 0.5f * (a1 + a2) / (float)COUT;
            ac += 1.f;
        }
    }
    if (l == 0){ accm[wid] = am; accc[wid] = ac; }
    __syncthreads();
    if (t == 0){
        float L = accm[0]+accm[1]+accm[2]+accm[3];
        float N = accc[0]+accc[1]+accc[2]+accc[3];
        out[0] = L / (N + 1e-7f) + 0.5f * (msep[0] / (float)((size_t)MTOT * COUT));
    }
}

extern "C" void kernel_launch(void* const* d_in, const int* in_sizes, int n_in,
                              void* d_out, int out_size, void* d_ws, size_t ws_size,
                              hipStream_t stream){
    (void)in_sizes; (void)n_in; (void)out_size; (void)ws_size;
    const float* s_feat = (const float*)d_in[0];
    const float* t_feat = (const float*)d_in[1];
    const int*   gt     = (const int*)d_in[2];
    const float* Wp     = (const float*)d_in[3];
    const float* gamma  = (const float*)d_in[4];
    const float* beta   = (const float*)d_in[5];
    char* ws = (char*)d_ws;

    // workspace layout
    u16*   SX   = (u16*)ws;                         // 83,886,080
    u16*   Wbf  = (u16*)(ws + 83886080);            // 163,840
    char*  z0   = ws + 84049920;
    float* bnsum    = (float*)(z0);                 // 1024
    float* bnsumsq  = (float*)(z0 + 1024);          // 1024
    float* gsum_s   = (float*)(z0 + 2048);          // 8*32*256*4 = 262144 each
    float* gsumsq_s = (float*)(z0 + 2048 + 262144);
    float* gsum_t   = (float*)(z0 + 2048 + 2*262144);
    float* gsumsq_t = (float*)(z0 + 2048 + 3*262144);
    float* msep     = (float*)(z0 + 1050624);       // 64
    float* counts   = (float*)(z0 + 1050688);       // 672 (+pad)
    float* bna      = (float*)(z0 + 1051712);       // 1024
    float* bnb      = (float*)(z0 + 1052736);       // 1024

    (void)hipMemsetAsync(z0, 0, 1051712, stream);   // sums + stats + mse + counts

    k0_wcvt  <<<80,    256,  0, stream>>>(Wp, Wbf);
    kt_strans<<<10240, 256,  0, stream>>>(s_feat, SX);
    k1_mfma  <<<1024,  256,  0, stream>>>(SX, Wbf, bnsum, bnsumsq);
    k2_bn    <<<1,     256,  0, stream>>>(bnsum, bnsumsq, gamma, beta, bna, bnb);
    k3_counts<<<256,   256,  0, stream>>>(gt, counts);
    k4_fused <<<256,   1024, 0, stream>>>(SX, t_feat, gt, bna, bnb,
                                          gsum_s, gsumsq_s, gsum_t, gsumsq_t, msep);
    k5_final <<<1,     256,  0, stream>>>(counts, gsum_s, gsumsq_s, gsum_t, gsumsq_t, msep, (float*)d_out);
}

// Round 6
// 536.202 us; speedup vs baseline: 1.9910x; 1.0049x over previous
//
#include <hip/hip_runtime.h>

typedef unsigned short u16;
typedef __attribute__((ext_vector_type(4))) float          f32x4;
typedef __attribute__((ext_vector_type(8))) short          bf8;
typedef __attribute__((ext_vector_type(8))) unsigned short us8;
typedef __attribute__((ext_vector_type(4))) unsigned short us4;

#define BATCH 8
#define CIN   320
#define COUT  256
#define NPIX  16384
#define NCLS  21
#define KCLS  32             // padded class rows for MFMA (rows 21..31 stay zero)
#define MTOT  (BATCH*NPIX)   // 131072
#define SROW  320            // u16 elements per SX row (s^T, later x in first 256)
#define STAT4 (4*KCLS*COUT)  // 32768 floats per block partial

__device__ __forceinline__ float bf2f(u16 v){
    unsigned int u = ((unsigned int)v) << 16;
    float f; __builtin_memcpy(&f, &u, 4); return f;
}
__device__ __forceinline__ u16 f2bf(float f){
    unsigned int u; __builtin_memcpy(&u, &f, 4);
    u += 0x7fffu + ((u >> 16) & 1u);
    return (u16)(u >> 16);
}

// swizzled u16 index into a [64px][256c] bf16 LDS tile.
__device__ __forceinline__ int swz_idx(int px, int c){
    return px * 256 + (c ^ (((px >> 3) & 3) << 4));
}

// ---------- K0: W fp32 [256][320] -> bf16 same layout ----------
__global__ void k0_wcvt(const float* __restrict__ W, u16* __restrict__ Wbf){
    int i4 = blockIdx.x * 256 + threadIdx.x;   // 20480 float4s exactly
    float4 v = reinterpret_cast<const float4*>(W)[i4];
    us4 o;
    o[0] = f2bf(v.x); o[1] = f2bf(v.y); o[2] = f2bf(v.z); o[3] = f2bf(v.w);
    reinterpret_cast<us4*>(Wbf)[i4] = o;
}

// ---------- KT: s_feat fp32 [b][320][P] -> SX bf16 [b*P][SROW] (transposed) ----------
__global__ __launch_bounds__(256) void kt_strans(const float* __restrict__ in, u16* __restrict__ out){
    __shared__ float tile[64*65];
    const int t  = threadIdx.x;
    const int bid = blockIdx.x;
    const int pt = bid & 255;          // 256 p-tiles of 64
    const int ct = (bid >> 8) % 5;     // 5 c-tiles of 64
    const int b  = bid / (256*5);
    const float* src = in + ((size_t)b*CIN + ct*64)*NPIX + pt*64;
    #pragma unroll
    for (int it = 0; it < 4; it++){
        int f = it*256 + t;
        int i = f >> 4, c4 = f & 15;
        float4 v = *reinterpret_cast<const float4*>(src + (size_t)i*NPIX + c4*4);
        float* d = &tile[i*65 + c4*4];
        d[0]=v.x; d[1]=v.y; d[2]=v.z; d[3]=v.w;
    }
    __syncthreads();
    u16* dst = out + ((size_t)(b*NPIX + pt*64))*SROW + ct*64;
    #pragma unroll
    for (int it = 0; it < 2; it++){
        int f = it*256 + t;
        int p = f >> 3, c8 = f & 7;
        us8 o;
        #pragma unroll
        for (int j = 0; j < 8; j++) o[j] = f2bf(tile[(c8*8+j)*65 + p]);
        *reinterpret_cast<us8*>(dst + (size_t)p*SROW + c8*8) = o;
    }
}

// ---------- K1: MFMA GEMM x[p][o] = sum_c SX[p][c]*W[o][c]; writes x bf16 in place; BN sums ----------
__global__ __launch_bounds__(256) void k1_mfma(u16* SX, const u16* __restrict__ Wbf,
                                               float* __restrict__ bnsum, float* __restrict__ bnsumsq){
    __shared__ __align__(16) char sm[67584];
    __shared__ float bns[512];
    const int t = threadIdx.x;
    const int wid = t >> 6, l = t & 63;
    const size_t pblk = (size_t)blockIdx.x * 128;
    const int wm = (wid & 1) * 64;
    const int wn = (wid >> 1) * 128;
    bns[t] = 0.f; bns[t+256] = 0.f;

    f32x4 acc[4][8];
    #pragma unroll
    for (int mi = 0; mi < 4; mi++)
        #pragma unroll
        for (int ni = 0; ni < 8; ni++)
            acc[mi][ni] = (f32x4){0.f,0.f,0.f,0.f};

    const int sg = t & 7, sp = t >> 3;
    const u16* srcb = SX + (pblk + sp) * SROW + sg * 8;
    us8 stg[4];
    #pragma unroll
    for (int it = 0; it < 4; it++)
        stg[it] = *reinterpret_cast<const us8*>(srcb + (size_t)it*32*SROW);

    for (int kt = 0; kt < 5; kt++){
        __syncthreads();
        #pragma unroll
        for (int it = 0; it < 4; it++){
            int p = sp + it*32;
            int byt = p*128 + ((sg*16) ^ ((p&7)<<4));
            *reinterpret_cast<us8*>(&sm[byt]) = stg[it];
        }
        if (kt < 4){
            #pragma unroll
            for (int it = 0; it < 4; it++)
                stg[it] = *reinterpret_cast<const us8*>(srcb + (size_t)it*32*SROW + (kt+1)*64);
        }
        __syncthreads();
        #pragma unroll
        for (int ks = 0; ks < 2; ks++){
            bf8 bfr[8], afr[4];
            const u16* wp = Wbf + (size_t)(wn + (l & 15)) * CIN + kt*64 + ks*32 + (l >> 4)*8;
            #pragma unroll
            for (int ni = 0; ni < 8; ni++)
                bfr[ni] = *reinterpret_cast<const bf8*>(wp + (size_t)ni*16*CIN);
            #pragma unroll
            for (int mi = 0; mi < 4; mi++){
                int p = wm + mi*16 + (l & 15);
                int byt = p*128 + (((ks*4 + (l>>4))*16) ^ ((p&7)<<4));
                afr[mi] = *reinterpret_cast<const bf8*>(&sm[byt]);
            }
            #pragma unroll
            for (int mi = 0; mi < 4; mi++)
                #pragma unroll
                for (int ni = 0; ni < 8; ni++)
                    acc[mi][ni] = __builtin_amdgcn_mfma_f32_16x16x32_bf16(afr[mi], bfr[ni], acc[mi][ni], 0, 0, 0);
        }
    }
    __syncthreads();
    #pragma unroll
    for (int mi = 0; mi < 4; mi++)
        #pragma unroll
        for (int ni = 0; ni < 8; ni++)
            #pragma unroll
            for (int r = 0; r < 4; r++){
                int p = wm + mi*16 + (l>>4)*4 + r;
                int o = wn + ni*16 + (l&15);
                *reinterpret_cast<u16*>(&sm[(p*264 + o)*2]) = f2bf(acc[mi][ni][r]);
            }
    __syncthreads();
    float s1[8], s2[8];
    #pragma unroll
    for (int j = 0; j < 8; j++){ s1[j] = 0.f; s2[j] = 0.f; }
    const int oc = (t & 31) * 8;
    const int pr = t >> 5;
    #pragma unroll
    for (int it = 0; it < 16; it++){
        int p = pr + it*8;
        us8 v = *reinterpret_cast<const us8*>(&sm[(p*264 + oc)*2]);
        *reinterpret_cast<us8*>(SX + (pblk + p)*SROW + oc) = v;
        #pragma unroll
        for (int j = 0; j < 8; j++){
            float fv = bf2f(v[j]);
            s1[j] += fv; s2[j] += fv*fv;
        }
    }
    #pragma unroll
    for (int j = 0; j < 8; j++){
        atomicAdd(&bns[oc + j],       s1[j]);
        atomicAdd(&bns[256 + oc + j], s2[j]);
    }
    __syncthreads();
    atomicAdd(&bnsum[t],   bns[t]);
    atomicAdd(&bnsumsq[t], bns[t + 256]);
}

// ---------- K2: BN affine coefficients ----------
__global__ void k2_bn(const float* __restrict__ bnsum, const float* __restrict__ bnsumsq,
                      const float* __restrict__ gamma, const float* __restrict__ beta,
                      float* __restrict__ bna, float* __restrict__ bnb){
    int o = threadIdx.x;
    float m = bnsum[o] / (float)MTOT;
    float v = bnsumsq[o] / (float)MTOT - m * m;
    float a = gamma[o] / sqrtf(v + 1e-5f);
    bna[o] = a;
    bnb[o] = beta[o] - m * a;
}

// ---------- K3: class histogram ----------
__global__ void k3_counts(const int* __restrict__ gt, float* __restrict__ counts){
    __shared__ float h[NCLS];
    const int b = blockIdx.x >> 5, seg = blockIdx.x & 31, t = threadIdx.x;
    if (t < NCLS) h[t] = 0.f;
    __syncthreads();
    const int* g = gt + b * NPIX + seg * 512;
    for (int i = t; i < 512; i += 256) atomicAdd(&h[g[i]], 1.0f);
    __syncthreads();
    if (t < NCLS) atomicAdd(&counts[b * NCLS + t], h[t]);
}

// ---------- K4: fused norm(s,t) + mse + class stats via one-hot MFMA ----------
__global__ __launch_bounds__(1024) void k4_fused(const u16* __restrict__ SX, const float* __restrict__ T,
                                                 const int* __restrict__ gt,
                                                 const float* __restrict__ bna, const float* __restrict__ bnb,
                                                 float* __restrict__ gss, float* __restrict__ gsq,
                                                 float* __restrict__ gts, float* __restrict__ gtq,
                                                 float* __restrict__ part,
                                                 float* __restrict__ msep){
    __shared__ float ts[COUT][65];     // raw t tile (f32), [c][px]
    __shared__ u16 sb[64*256];         // s_bar bf16 tile, [px][c] swizzled
    __shared__ u16 tb[64*256];         // t_bar bf16 tile
    __shared__ int gtile[64];
    __shared__ float msw[16];
    const int t = threadIdx.x, wid = t >> 6, l = t & 63;
    const int b  = blockIdx.x >> 5;
    const int pb = (blockIdx.x & 31) * 512;
    const float a0=bna[l], a1=bna[l+64], a2=bna[l+128], a3=bna[l+192];
    const float c0=bnb[l], c1=bnb[l+64], c2=bnb[l+128], c3=bnb[l+192];
    const float* Tb = T + (size_t)b * COUT * NPIX;
    const int* gtb = gt + b * NPIX;
    const u16* Xb = SX + (size_t)b * NPIX * SROW;
    float msea = 0.f;

    // stats accumulators: [type: 0=s,1=s^2,2=t,3=t^2][mtile]
    f32x4 acc[4][2];
    #pragma unroll
    for (int ty = 0; ty < 4; ty++)
        #pragma unroll
        for (int mt = 0; mt < 2; mt++)
            acc[ty][mt] = (f32x4){0.f,0.f,0.f,0.f};

    const int sc = t >> 4, sp4 = t & 15;
    float4 stg[4];
    int gstg = 0;
    {
        #pragma unroll
        for (int it = 0; it < 4; it++)
            stg[it] = *reinterpret_cast<const float4*>(Tb + (size_t)(it*64 + sc)*NPIX + pb + sp4*4);
        if (t < 64) gstg = gtb[pb + t];
    }

    for (int tile = 0; tile < 8; tile++){
        const int q0 = pb + tile*64;
        #pragma unroll
        for (int it = 0; it < 4; it++){
            float4 v = stg[it];
            float* d = &ts[it*64 + sc][sp4*4];
            d[0]=v.x; d[1]=v.y; d[2]=v.z; d[3]=v.w;
        }
        if (t < 64) gtile[t] = gstg;
        __syncthreads();

        // ---- norm phase ----
        {
            float sq[4][4], tq[4][4], ns[4], nt[4];
            #pragma unroll
            for (int u = 0; u < 4; u++){
                const int pp = wid*4 + u;
                const u16* xr = Xb + (size_t)(q0 + pp) * SROW;
                sq[u][0] = fmaxf(fmaf(a0, bf2f(xr[l]),     c0), 0.f);
                sq[u][1] = fmaxf(fmaf(a1, bf2f(xr[l+64]),  c1), 0.f);
                sq[u][2] = fmaxf(fmaf(a2, bf2f(xr[l+128]), c2), 0.f);
                sq[u][3] = fmaxf(fmaf(a3, bf2f(xr[l+192]), c3), 0.f);
                tq[u][0] = ts[l][pp];     tq[u][1] = ts[l+64][pp];
                tq[u][2] = ts[l+128][pp]; tq[u][3] = ts[l+192][pp];
                ns[u] = sq[u][0]*sq[u][0] + sq[u][1]*sq[u][1] + sq[u][2]*sq[u][2] + sq[u][3]*sq[u][3];
                nt[u] = tq[u][0]*tq[u][0] + tq[u][1]*tq[u][1] + tq[u][2]*tq[u][2] + tq[u][3]*tq[u][3];
            }
            #pragma unroll
            for (int off = 32; off; off >>= 1){
                #pragma unroll
                for (int u = 0; u < 4; u++){
                    ns[u] += __shfl_xor(ns[u], off, 64);
                    nt[u] += __shfl_xor(nt[u], off, 64);
                }
            }
            #pragma unroll
            for (int u = 0; u < 4; u++){
                const int pp = wid*4 + u;
                const int swz = ((pp >> 3) & 3) << 4;
                const int base = pp * 256;
                float rs = 1.0f / fmaxf(sqrtf(ns[u]), 1e-12f);
                float rt = 1.0f / fmaxf(sqrtf(nt[u]), 1e-12f);
                #pragma unroll
                for (int m = 0; m < 4; m++){
                    float sv = sq[u][m] * rs;
                    float tv = tq[u][m] * rt;
                    sb[base + ((l + 64*m) ^ swz)] = f2bf(sv);
                    tb[base + ((l + 64*m) ^ swz)] = f2bf(tv);
                    float d = sv - tv;
                    msea += d * d;
                }
            }
        }
        __syncthreads();

        if (tile < 7){
            const int q1 = q0 + 64;
            #pragma unroll
            for (int it = 0; it < 4; it++)
                stg[it] = *reinterpret_cast<const float4*>(Tb + (size_t)(it*64 + sc)*NPIX + q1 + sp4*4);
            if (t < 64) gstg = gtb[q1 + t];
        }

        // ---- MFMA stats phase ----
        {
            const int cw = wid*16 + (l & 15);
            const int g  = l >> 4;
            #pragma unroll
            for (int ks = 0; ks < 2; ks++){
                int gv[8];
                #pragma unroll
                for (int j = 0; j < 8; j++) gv[j] = gtile[ks*32 + g*8 + j];
                bf8 bS, bT, bS2, bT2;
                #pragma unroll
                for (int j = 0; j < 8; j++){
                    int px = ks*32 + g*8 + j;
                    int idx = swz_idx(px, cw);
                    u16 vs = sb[idx], vt = tb[idx];
                    bS[j] = (short)vs; bT[j] = (short)vt;
                    float fs = bf2f(vs), ft = bf2f(vt);
                    bS2[j] = (short)f2bf(fs * fs);
                    bT2[j] = (short)f2bf(ft * ft);
                }
                bf8 aA0, aA1;
                #pragma unroll
                for (int j = 0; j < 8; j++){
                    aA0[j] = (short)((gv[j] == (l & 15))      ? 0x3F80 : 0);
                    aA1[j] = (short)((gv[j] == (l & 15) + 16) ? 0x3F80 : 0);
                }
                acc[0][0] = __builtin_amdgcn_mfma_f32_16x16x32_bf16(aA0, bS,  acc[0][0], 0,0,0);
                acc[0][1] = __builtin_amdgcn_mfma_f32_16x16x32_bf16(aA1, bS,  acc[0][1], 0,0,0);
                acc[1][0] = __builtin_amdgcn_mfma_f32_16x16x32_bf16(aA0, bS2, acc[1][0], 0,0,0);
                acc[1][1] = __builtin_amdgcn_mfma_f32_16x16x32_bf16(aA1, bS2, acc[1][1], 0,0,0);
                acc[2][0] = __builtin_amdgcn_mfma_f32_16x16x32_bf16(aA0, bT,  acc[2][0], 0,0,0);
                acc[2][1] = __builtin_amdgcn_mfma_f32_16x16x32_bf16(aA1, bT,  acc[2][1], 0,0,0);
                acc[3][0] = __builtin_amdgcn_mfma_f32_16x16x32_bf16(aA0, bT2, acc[3][0], 0,0,0);
                acc[3][1] = __builtin_amdgcn_mfma_f32_16x16x32_bf16(aA1, bT2, acc[3][1], 0,0,0);
            }
        }
        __syncthreads();
    }

    // ---- epilogue: stats out ----
    {
        const int cw = wid*16 + (l & 15);
        if (part){
            // plain coalesced per-block partial writes (no atomics)
            float* PP = part + (size_t)blockIdx.x * STAT4;
            #pragma unroll
            for (int ty = 0; ty < 4; ty++)
                #pragma unroll
                for (int mt = 0; mt < 2; mt++)
                    #pragma unroll
                    for (int r = 0; r < 4; r++){
                        int k = mt*16 + (l>>4)*4 + r;
                        PP[ty*KCLS*COUT + k*COUT + cw] = acc[ty][mt][r];
                    }
        } else {
            float* G[4] = { gss + (size_t)b*KCLS*COUT, gsq + (size_t)b*KCLS*COUT,
                            gts + (size_t)b*KCLS*COUT, gtq + (size_t)b*KCLS*COUT };
            #pragma unroll
            for (int ty = 0; ty < 4; ty++)
                #pragma unroll
                for (int mt = 0; mt < 2; mt++)
                    #pragma unroll
                    for (int r = 0; r < 4; r++){
                        int k = mt*16 + (l>>4)*4 + r;
                        atomicAdd(&G[ty][k*COUT + cw], acc[ty][mt][r]);
                    }
        }
    }
    // ---- mse reduce ----
    #pragma unroll
    for (int off = 32; off; off >>= 1) msea += __shfl_xor(msea, off, 64);
    if (l == 0) msw[wid] = msea;
    __syncthreads();
    if (t == 0){
        float v = 0.f;
        #pragma unroll
        for (int i = 0; i < 16; i++) v += msw[i];
        atomicAdd(msep, v);
    }
}

// ---------- KR: reduce 32 per-block partials per batch -> stat buffers ----------
__global__ void kR_reduce(const float* __restrict__ part,
                          float* __restrict__ gss, float* __restrict__ gsq,
                          float* __restrict__ gts, float* __restrict__ gtq){
    int g = blockIdx.x * 256 + threadIdx.x;           // 65536 threads, 262144 elems
    #pragma unroll
    for (int it = 0; it < 4; it++, g += 65536){
        int c  = g & 255;
        int k  = (g >> 8) & 31;
        int ty = (g >> 13) & 3;
        int b  = g >> 15;
        const float* p = part + (size_t)(b*32) * STAT4 + ty*KCLS*COUT + k*COUT + c;
        float s = 0.f;
        #pragma unroll
        for (int sl = 0; sl < 32; sl++) s += p[(size_t)sl * STAT4];
        float* G = (ty==0)? gss : (ty==1)? gsq : (ty==2)? gts : gtq;
        G[(b*KCLS + k)*COUT + c] = s;
    }
}

// ---------- K5: final scalar loss ----------
__global__ void k5_final(const float* __restrict__ counts,
                         const float* __restrict__ gs,  const float* __restrict__ gqs,
                         const float* __restrict__ gtm, const float* __restrict__ gqt,
                         const float* __restrict__ msep, float* __restrict__ out){
    __shared__ float accm[4], accc[4];
    const int t = threadIdx.x, wid = t >> 6, l = t & 63;
    float am = 0.f, ac = 0.f;
    for (int i = 0; i < 42; i++){
        int bk = wid*42 + i;                 // 168 = 4 waves * 42
        float cnt = counts[bk];
        int b = bk / NCLS, k = bk - b*NCLS;
        float cs = fmaxf(cnt, 1.f);
        float dn = fmaxf(cnt - 1.f, 1.f);
        float a1 = 0.f, a2 = 0.f;
        #pragma unroll
        for (int q = 0; q < 4; q++){
            int idx = (b*KCLS + k)*COUT + l + q*64;
            float mus = gs[idx] / cs;
            float vas = (gqs[idx] - cnt*mus*mus) / dn + 1e-6f;
            float mut = gtm[idx] / cs;
            float vat = (gqt[idx] - cnt*mut*mut) / dn + 1e-6f;
            float dm = mus - mut, dv = vas - vat;
            a1 += dm*dm; a2 += dv*dv;
        }
        #pragma unroll
        for (int off = 32; off; off >>= 1){ a1 += __shfl_xor(a1, off, 64); a2 += __shfl_xor(a2, off, 64); }
        if (l == 0 && cnt > 1.f && k != 0){
            am += 0.5f * (a1 + a2) / (float)COUT;
            ac += 1.f;
        }
    }
    if (l == 0){ accm[wid] = am; accc[wid] = ac; }
    __syncthreads();
    if (t == 0){
        float L = accm[0]+accm[1]+accm[2]+accm[3];
        float N = accc[0]+accc[1]+accc[2]+accc[3];
        out[0] = L / (N + 1e-7f) + 0.5f * (msep[0] / (float)((size_t)MTOT * COUT));
    }
}

extern "C" void kernel_launch(void* const* d_in, const int* in_sizes, int n_in,
                              void* d_out, int out_size, void* d_ws, size_t ws_size,
                              hipStream_t stream){
    (void)in_sizes; (void)n_in; (void)out_size;
    const float* s_feat = (const float*)d_in[0];
    const float* t_feat = (const float*)d_in[1];
    const int*   gt     = (const int*)d_in[2];
    const float* Wp     = (const float*)d_in[3];
    const float* gamma  = (const float*)d_in[4];
    const float* beta   = (const float*)d_in[5];
    char* ws = (char*)d_ws;

    // workspace layout
    u16*   SX   = (u16*)ws;                         // 83,886,080
    u16*   Wbf  = (u16*)(ws + 83886080);            // 163,840
    char*  z0   = ws + 84049920;
    float* bnsum    = (float*)(z0);                 // 1024
    float* bnsumsq  = (float*)(z0 + 1024);          // 1024
    float* msep     = (float*)(z0 + 2048);          // 256 (pad)
    float* counts   = (float*)(z0 + 2304);          // 1024 (pad)
    float* bna      = (float*)(z0 + 3328);          // 1024
    float* bnb      = (float*)(z0 + 4352);          // 1024
    float* gsum_s   = (float*)(z0 + 5376);          // 4 x 262144
    float* gsumsq_s = (float*)(z0 + 5376 + 262144);
    float* gsum_t   = (float*)(z0 + 5376 + 2*262144);
    float* gsumsq_t = (float*)(z0 + 5376 + 3*262144);
    float* part     = (float*)(z0 + 1054720);       // 256 x 131072B = 33,554,432
    const size_t NEEDED = 84049920ULL + 1054720ULL + 33554432ULL;   // 118,659,072
    const bool use_part = (ws_size >= NEEDED);

    (void)hipMemsetAsync(z0, 0, 3328, stream);                       // bn sums + mse + counts
    if (!use_part) (void)hipMemsetAsync(z0 + 5376, 0, 1048576, stream);  // stats (atomic path)

    k0_wcvt  <<<80,    256,  0, stream>>>(Wp, Wbf);
    kt_strans<<<10240, 256,  0, stream>>>(s_feat, SX);
    k1_mfma  <<<1024,  256,  0, stream>>>(SX, Wbf, bnsum, bnsumsq);
    k2_bn    <<<1,     256,  0, stream>>>(bnsum, bnsumsq, gamma, beta, bna, bnb);
    k3_counts<<<256,   256,  0, stream>>>(gt, counts);
    k4_fused <<<256,   1024, 0, stream>>>(SX, t_feat, gt, bna, bnb,
                                          gsum_s, gsumsq_s, gsum_t, gsumsq_t,
                                          use_part ? part : nullptr, msep);
    if (use_part)
        kR_reduce<<<256, 256, 0, stream>>>(part, gsum_s, gsumsq_s, gsum_t, gsumsq_t);
    k5_final <<<1,     256,  0, stream>>>(counts, gsum_s, gsumsq_s, gsum_t, gsumsq_t, msep, (float*)d_out);
}

// Round 7
// 520.088 us; speedup vs baseline: 2.0526x; 1.0310x over previous
//
#include <hip/hip_runtime.h>

typedef unsigned short u16;
typedef __attribute__((ext_vector_type(4))) float          f32x4;
typedef __attribute__((ext_vector_type(8))) short          bf8;
typedef __attribute__((ext_vector_type(8))) unsigned short us8;
typedef __attribute__((ext_vector_type(4))) unsigned short us4;

#define BATCH 8
#define CIN   320
#define COUT  256
#define NPIX  16384
#define NCLS  21
#define KCLS  32             // padded class rows for MFMA (rows 21..31 stay zero)
#define MTOT  (BATCH*NPIX)   // 131072
#define SROW  320            // u16 per SX row: x in cols 0..255, partial-stats pad in 256..319

__device__ __forceinline__ float bf2f(u16 v){
    unsigned int u = ((unsigned int)v) << 16;
    float f; __builtin_memcpy(&f, &u, 4); return f;
}
__device__ __forceinline__ u16 f2bf(float f){
    unsigned int u; __builtin_memcpy(&u, &f, 4);
    u += 0x7fffu + ((u >> 16) & 1u);
    return (u16)(u >> 16);
}

// swizzled u16 index into a [64px][256c] bf16 LDS tile (k4).
__device__ __forceinline__ int swz_idx(int px, int c){
    return px * 256 + (c ^ (((px >> 3) & 3) << 4));
}

// ---------- K0: W fp32 [256][320] -> bf16 same layout ----------
__global__ void k0_wcvt(const float* __restrict__ W, u16* __restrict__ Wbf){
    int i4 = blockIdx.x * 256 + threadIdx.x;   // 20480 float4s exactly
    float4 v = reinterpret_cast<const float4*>(W)[i4];
    us4 o;
    o[0] = f2bf(v.x); o[1] = f2bf(v.y); o[2] = f2bf(v.z); o[3] = f2bf(v.w);
    reinterpret_cast<us4*>(Wbf)[i4] = o;
}

// ---------- K1: fused transpose+cvt+MFMA GEMM x[p][o] = sum_c s[b][c][p]*W[o][c] ----------
// reads s_feat f32 directly; writes x bf16 into SX cols 0..255; BN sums.
__global__ __launch_bounds__(256) void k1_mfma(const float* __restrict__ S, const u16* __restrict__ Wbf,
                                               u16* __restrict__ SX,
                                               float* __restrict__ bnsum, float* __restrict__ bnsumsq){
    __shared__ __align__(16) char sm[67584];   // K-loop: A-tile [128px][128B swz]; epilogue: Xs[128][264] bf16
    __shared__ float bns[512];
    const int t = threadIdx.x;
    const int wid = t >> 6, l = t & 63;
    const size_t pblk = (size_t)blockIdx.x * 128;
    const int b  = (int)(pblk >> 14);          // 16384 px per batch
    const int p0 = (int)(pblk & 16383);
    const int wm = (wid & 1) * 64;
    const int wn = (wid >> 1) * 128;
    bns[t] = 0.f; bns[t+256] = 0.f;

    f32x4 acc[4][8];
    #pragma unroll
    for (int mi = 0; mi < 4; mi++)
        #pragma unroll
        for (int ni = 0; ni < 8; ni++)
            acc[mi][ni] = (f32x4){0.f,0.f,0.f,0.f};

    // staging: thread -> (c-octet c8 = t&7, px-quad px4 = t>>3)
    const int c8 = t & 7, px4 = t >> 3;
    const float* Sg = S + ((size_t)b * CIN + c8*8) * NPIX + p0 + px4*4;
    f32x4 stg[8];
    #pragma unroll
    for (int cj = 0; cj < 8; cj++)
        stg[cj] = *reinterpret_cast<const f32x4*>(Sg + (size_t)cj * NPIX);

    for (int kt = 0; kt < 5; kt++){
        __syncthreads();                       // LDS free (prev compute done)
        #pragma unroll
        for (int pxj = 0; pxj < 4; pxj++){     // cvt + swizzled LDS write
            int px = px4*4 + pxj;
            us8 o;
            #pragma unroll
            for (int cj = 0; cj < 8; cj++) o[cj] = f2bf(stg[cj][pxj]);
            int byt = px*128 + ((c8*16) ^ ((px&7)<<4));
            *reinterpret_cast<us8*>(&sm[byt]) = o;
        }
        if (kt < 4){                           // prefetch next K-tile (overlaps compute)
            #pragma unroll
            for (int cj = 0; cj < 8; cj++)
                stg[cj] = *reinterpret_cast<const f32x4*>(Sg + (size_t)((kt+1)*64 + cj) * NPIX);
        }
        __syncthreads();                       // tile ready
        #pragma unroll
        for (int ks = 0; ks < 2; ks++){
            bf8 bfr[8], afr[4];
            const u16* wp = Wbf + (size_t)(wn + (l & 15)) * CIN + kt*64 + ks*32 + (l >> 4)*8;
            #pragma unroll
            for (int ni = 0; ni < 8; ni++)
                bfr[ni] = *reinterpret_cast<const bf8*>(wp + (size_t)ni*16*CIN);
            #pragma unroll
            for (int mi = 0; mi < 4; mi++){
                int p = wm + mi*16 + (l & 15);
                int byt = p*128 + (((ks*4 + (l>>4))*16) ^ ((p&7)<<4));
                afr[mi] = *reinterpret_cast<const bf8*>(&sm[byt]);
            }
            #pragma unroll
            for (int mi = 0; mi < 4; mi++)
                #pragma unroll
                for (int ni = 0; ni < 8; ni++)
                    acc[mi][ni] = __builtin_amdgcn_mfma_f32_16x16x32_bf16(afr[mi], bfr[ni], acc[mi][ni], 0, 0, 0);
        }
    }
    __syncthreads();
    // acc -> Xs [128][264] bf16
    #pragma unroll
    for (int mi = 0; mi < 4; mi++)
        #pragma unroll
        for (int ni = 0; ni < 8; ni++)
            #pragma unroll
            for (int r = 0; r < 4; r++){
                int p = wm + mi*16 + (l>>4)*4 + r;
                int o = wn + ni*16 + (l&15);
                *reinterpret_cast<u16*>(&sm[(p*264 + o)*2]) = f2bf(acc[mi][ni][r]);
            }
    __syncthreads();
    // coalesced readback -> SX rows (stride SROW) + BN partial sums
    float s1[8], s2[8];
    #pragma unroll
    for (int j = 0; j < 8; j++){ s1[j] = 0.f; s2[j] = 0.f; }
    const int oc = (t & 31) * 8;
    const int pr = t >> 5;
    #pragma unroll
    for (int it = 0; it < 16; it++){
        int p = pr + it*8;
        us8 v = *reinterpret_cast<const us8*>(&sm[(p*264 + oc)*2]);
        *reinterpret_cast<us8*>(SX + (pblk + p)*SROW + oc) = v;
        #pragma unroll
        for (int j = 0; j < 8; j++){
            float fv = bf2f(v[j]);
            s1[j] += fv; s2[j] += fv*fv;
        }
    }
    #pragma unroll
    for (int j = 0; j < 8; j++){
        atomicAdd(&bns[oc + j],       s1[j]);
        atomicAdd(&bns[256 + oc + j], s2[j]);
    }
    __syncthreads();
    atomicAdd(&bnsum[t],   bns[t]);
    atomicAdd(&bnsumsq[t], bns[t + 256]);
}

// ---------- K2: BN affine coefficients ----------
__global__ void k2_bn(const float* __restrict__ bnsum, const float* __restrict__ bnsumsq,
                      const float* __restrict__ gamma, const float* __restrict__ beta,
                      float* __restrict__ bna, float* __restrict__ bnb){
    int o = threadIdx.x;
    float m = bnsum[o] / (float)MTOT;
    float v = bnsumsq[o] / (float)MTOT - m * m;
    float a = gamma[o] / sqrtf(v + 1e-5f);
    bna[o] = a;
    bnb[o] = beta[o] - m * a;
}

// ---------- K3: class histogram ----------
__global__ void k3_counts(const int* __restrict__ gt, float* __restrict__ counts){
    __shared__ float h[NCLS];
    const int b = blockIdx.x >> 5, seg = blockIdx.x & 31, t = threadIdx.x;
    if (t < NCLS) h[t] = 0.f;
    __syncthreads();
    const int* g = gt + b * NPIX + seg * 512;
    for (int i = t; i < 512; i += 256) atomicAdd(&h[g[i]], 1.0f);
    __syncthreads();
    if (t < NCLS) atomicAdd(&counts[b * NCLS + t], h[t]);
}

// ---------- K4: fused norm(s,t) + mse + class stats via one-hot MFMA ----------
// per-block partial stats written as bf16 into SX's own rows, cols 256..319 (no atomics, no extra ws)
__global__ __launch_bounds__(1024) void k4_fused(u16* __restrict__ SX, const float* __restrict__ T,
                                                 const int* __restrict__ gt,
                                                 const float* __restrict__ bna, const float* __restrict__ bnb,
                                                 float* __restrict__ msep){
    __shared__ float ts[COUT][65];     // raw t tile (f32), [c][px]
    __shared__ u16 sb[64*256];         // s_bar bf16 tile, [px][c] swizzled
    __shared__ u16 tb[64*256];         // t_bar bf16 tile
    __shared__ int gtile[64];
    __shared__ float msw[16];
    const int t = threadIdx.x, wid = t >> 6, l = t & 63;
    const int b  = blockIdx.x >> 5;
    const int pb = (blockIdx.x & 31) * 512;
    const float a0=bna[l], a1=bna[l+64], a2=bna[l+128], a3=bna[l+192];
    const float c0=bnb[l], c1=bnb[l+64], c2=bnb[l+128], c3=bnb[l+192];
    const float* Tb = T + (size_t)b * COUT * NPIX;
    const int* gtb = gt + b * NPIX;
    const u16* Xb = SX + (size_t)b * NPIX * SROW;
    float msea = 0.f;

    // stats accumulators: [type: 0=s,1=s^2,2=t,3=t^2][mtile]
    f32x4 acc[4][2];
    #pragma unroll
    for (int ty = 0; ty < 4; ty++)
        #pragma unroll
        for (int mt = 0; mt < 2; mt++)
            acc[ty][mt] = (f32x4){0.f,0.f,0.f,0.f};

    const int sc = t >> 4, sp4 = t & 15;
    float4 stg[4];
    int gstg = 0;
    {
        #pragma unroll
        for (int it = 0; it < 4; it++)
            stg[it] = *reinterpret_cast<const float4*>(Tb + (size_t)(it*64 + sc)*NPIX + pb + sp4*4);
        if (t < 64) gstg = gtb[pb + t];
    }

    for (int tile = 0; tile < 8; tile++){
        const int q0 = pb + tile*64;
        #pragma unroll
        for (int it = 0; it < 4; it++){
            float4 v = stg[it];
            float* d = &ts[it*64 + sc][sp4*4];
            d[0]=v.x; d[1]=v.y; d[2]=v.z; d[3]=v.w;
        }
        if (t < 64) gtile[t] = gstg;
        __syncthreads();

        // ---- norm phase ----
        {
            float sq[4][4], tq[4][4], ns[4], nt[4];
            #pragma unroll
            for (int u = 0; u < 4; u++){
                const int pp = wid*4 + u;
                const u16* xr = Xb + (size_t)(q0 + pp) * SROW;
                sq[u][0] = fmaxf(fmaf(a0, bf2f(xr[l]),     c0), 0.f);
                sq[u][1] = fmaxf(fmaf(a1, bf2f(xr[l+64]),  c1), 0.f);
                sq[u][2] = fmaxf(fmaf(a2, bf2f(xr[l+128]), c2), 0.f);
                sq[u][3] = fmaxf(fmaf(a3, bf2f(xr[l+192]), c3), 0.f);
                tq[u][0] = ts[l][pp];     tq[u][1] = ts[l+64][pp];
                tq[u][2] = ts[l+128][pp]; tq[u][3] = ts[l+192][pp];
                ns[u] = sq[u][0]*sq[u][0] + sq[u][1]*sq[u][1] + sq[u][2]*sq[u][2] + sq[u][3]*sq[u][3];
                nt[u] = tq[u][0]*tq[u][0] + tq[u][1]*tq[u][1] + tq[u][2]*tq[u][2] + tq[u][3]*tq[u][3];
            }
            #pragma unroll
            for (int off = 32; off; off >>= 1){
                #pragma unroll
                for (int u = 0; u < 4; u++){
                    ns[u] += __shfl_xor(ns[u], off, 64);
                    nt[u] += __shfl_xor(nt[u], off, 64);
                }
            }
            #pragma unroll
            for (int u = 0; u < 4; u++){
                const int pp = wid*4 + u;
                const int swz = ((pp >> 3) & 3) << 4;
                const int base = pp * 256;
                float rs = 1.0f / fmaxf(sqrtf(ns[u]), 1e-12f);
                float rt = 1.0f / fmaxf(sqrtf(nt[u]), 1e-12f);
                #pragma unroll
                for (int m = 0; m < 4; m++){
                    float sv = sq[u][m] * rs;
                    float tv = tq[u][m] * rt;
                    sb[base + ((l + 64*m) ^ swz)] = f2bf(sv);
                    tb[base + ((l + 64*m) ^ swz)] = f2bf(tv);
                    float d = sv - tv;
                    msea += d * d;
                }
            }
        }
        __syncthreads();

        if (tile < 7){
            const int q1 = q0 + 64;
            #pragma unroll
            for (int it = 0; it < 4; it++)
                stg[it] = *reinterpret_cast<const float4*>(Tb + (size_t)(it*64 + sc)*NPIX + q1 + sp4*4);
            if (t < 64) gstg = gtb[q1 + t];
        }

        // ---- MFMA stats phase ----
        {
            const int cw = wid*16 + (l & 15);
            const int g  = l >> 4;
            #pragma unroll
            for (int ks = 0; ks < 2; ks++){
                int gv[8];
                #pragma unroll
                for (int j = 0; j < 8; j++) gv[j] = gtile[ks*32 + g*8 + j];
                bf8 bS, bT, bS2, bT2;
                #pragma unroll
                for (int j = 0; j < 8; j++){
                    int px = ks*32 + g*8 + j;
                    int idx = swz_idx(px, cw);
                    u16 vs = sb[idx], vt = tb[idx];
                    bS[j] = (short)vs; bT[j] = (short)vt;
                    float fs = bf2f(vs), ft = bf2f(vt);
                    bS2[j] = (short)f2bf(fs * fs);
                    bT2[j] = (short)f2bf(ft * ft);
                }
                bf8 aA0, aA1;
                #pragma unroll
                for (int j = 0; j < 8; j++){
                    aA0[j] = (short)((gv[j] == (l & 15))      ? 0x3F80 : 0);
                    aA1[j] = (short)((gv[j] == (l & 15) + 16) ? 0x3F80 : 0);
                }
                acc[0][0] = __builtin_amdgcn_mfma_f32_16x16x32_bf16(aA0, bS,  acc[0][0], 0,0,0);
                acc[0][1] = __builtin_amdgcn_mfma_f32_16x16x32_bf16(aA1, bS,  acc[0][1], 0,0,0);
                acc[1][0] = __builtin_amdgcn_mfma_f32_16x16x32_bf16(aA0, bS2, acc[1][0], 0,0,0);
                acc[1][1] = __builtin_amdgcn_mfma_f32_16x16x32_bf16(aA1, bS2, acc[1][1], 0,0,0);
                acc[2][0] = __builtin_amdgcn_mfma_f32_16x16x32_bf16(aA0, bT,  acc[2][0], 0,0,0);
                acc[2][1] = __builtin_amdgcn_mfma_f32_16x16x32_bf16(aA1, bT,  acc[2][1], 0,0,0);
                acc[3][0] = __builtin_amdgcn_mfma_f32_16x16x32_bf16(aA0, bT2, acc[3][0], 0,0,0);
                acc[3][1] = __builtin_amdgcn_mfma_f32_16x16x32_bf16(aA1, bT2, acc[3][1], 0,0,0);
            }
        }
        __syncthreads();
    }

    // ---- epilogue: bf16 partials into own rows' padding (cols 256..319), no atomics ----
    {
        const int cw = wid*16 + (l & 15);
        u16* Pb = SX + (size_t)blockIdx.x * 512 * SROW;   // this block's 512 rows
        #pragma unroll
        for (int ty = 0; ty < 4; ty++)
            #pragma unroll
            for (int mt = 0; mt < 2; mt++)
                #pragma unroll
                for (int r = 0; r < 4; r++){
                    int k = mt*16 + (l>>4)*4 + r;
                    int i = (ty*KCLS + k)*COUT + cw;       // 0..32767
                    Pb[(size_t)(i >> 6)*SROW + 256 + (i & 63)] = f2bf(acc[ty][mt][r]);
                }
    }
    // ---- mse reduce ----
    #pragma unroll
    for (int off = 32; off; off >>= 1) msea += __shfl_xor(msea, off, 64);
    if (l == 0) msw[wid] = msea;
    __syncthreads();
    if (t == 0){
        float v = 0.f;
        #pragma unroll
        for (int i = 0; i < 16; i++) v += msw[i];
        atomicAdd(msep, v);
    }
}

// ---------- KR: gather bf16 partials from SX padding -> f32 stat buffers ----------
__global__ void kR_reduce(const u16* __restrict__ SX,
                          float* __restrict__ gss, float* __restrict__ gsq,
                          float* __restrict__ gts, float* __restrict__ gtq){
    int g = blockIdx.x * 256 + threadIdx.x;           // 65536 threads, 262144 elems
    #pragma unroll
    for (int it = 0; it < 4; it++, g += 65536){
        int c  = g & 255;
        int k  = (g >> 8) & 31;
        int ty = (g >> 13) & 3;
        int b  = g >> 15;
        int i  = (ty*KCLS + k)*COUT + c;
        const u16* p = SX + (size_t)(b*32) * 512 * SROW + (size_t)(i >> 6)*SROW + 256 + (i & 63);
        float s = 0.f;
        #pragma unroll
        for (int sl = 0; sl < 32; sl++) s += bf2f(p[(size_t)sl * 512 * SROW]);
        float* G = (ty==0)? gss : (ty==1)? gsq : (ty==2)? gts : gtq;
        G[(b*KCLS + k)*COUT + c] = s;
    }
}

// ---------- K5: final scalar loss ----------
__global__ void k5_final(const float* __restrict__ counts,
                         const float* __restrict__ gs,  const float* __restrict__ gqs,
                         const float* __restrict__ gtm, const float* __restrict__ gqt,
                         const float* __restrict__ msep, float* __restrict__ out){
    __shared__ float accm[4], accc[4];
    const int t = threadIdx.x, wid = t >> 6, l = t & 63;
    float am = 0.f, ac = 0.f;
    for (int i = 0; i < 42; i++){
        int bk = wid*42 + i;                 // 168 = 4 waves * 42
        float cnt = counts[bk];
        int b = bk / NCLS, k = bk - b*NCLS;
        float cs = fmaxf(cnt, 1.f);
        float dn = fmaxf(cnt - 1.f, 1.f);
        float a1 = 0.f, a2 = 0.f;
        #pragma unroll
        for (int q = 0; q < 4; q++){
            int idx = (b*KCLS + k)*COUT + l + q*64;
            float mus = gs[idx] / cs;
            float vas = (gqs[idx] - cnt*mus*mus) / dn + 1e-6f;
            float mut = gtm[idx] / cs;
            float vat = (gqt[idx] - cnt*mut*mut) / dn + 1e-6f;
            float dm = mus - mut, dv = vas - vat;
            a1 += dm*dm; a2 += dv*dv;
        }
        #pragma unroll
        for (int off = 32; off; off >>= 1){ a1 += __shfl_xor(a1, off, 64); a2 += __shfl_xor(a2, off, 64); }
        if (l == 0 && cnt > 1.f && k != 0){
            am += 0.5f * (a1 + a2) / (float)COUT;
            ac += 1.f;
        }
    }
    if (l == 0){ accm[wid] = am; accc[wid] = ac; }
    __syncthreads();
    if (t == 0){
        float L = accm[0]+accm[1]+accm[2]+accm[3];
        float N = accc[0]+accc[1]+accc[2]+accc[3];
        out[0] = L / (N + 1e-7f) + 0.5f * (msep[0] / (float)((size_t)MTOT * COUT));
    }
}

extern "C" void kernel_launch(void* const* d_in, const int* in_sizes, int n_in,
                              void* d_out, int out_size, void* d_ws, size_t ws_size,
                              hipStream_t stream){
    (void)in_sizes; (void)n_in; (void)out_size; (void)ws_size;
    const float* s_feat = (const float*)d_in[0];
    const float* t_feat = (const float*)d_in[1];
    const int*   gt     = (const int*)d_in[2];
    const float* Wp     = (const float*)d_in[3];
    const float* gamma  = (const float*)d_in[4];
    const float* beta   = (const float*)d_in[5];
    char* ws = (char*)d_ws;

    // workspace layout (total ~85.1 MB)
    u16*   SX   = (u16*)ws;                         // 83,886,080 (x + partial-stat padding)
    u16*   Wbf  = (u16*)(ws + 83886080);            // 163,840
    char*  z0   = ws + 84049920;
    float* bnsum    = (float*)(z0);                 // 1024
    float* bnsumsq  = (float*)(z0 + 1024);          // 1024
    float* msep     = (float*)(z0 + 2048);          // 256 (pad)
    float* counts   = (float*)(z0 + 2304);          // 1024 (pad)
    float* bna      = (float*)(z0 + 3328);          // 1024
    float* bnb      = (float*)(z0 + 4352);          // 1024
    float* gsum_s   = (float*)(z0 + 5376);          // 4 x 262144 (written fully by kR)
    float* gsumsq_s = (float*)(z0 + 5376 + 262144);
    float* gsum_t   = (float*)(z0 + 5376 + 2*262144);
    float* gsumsq_t = (float*)(z0 + 5376 + 3*262144);

    (void)hipMemsetAsync(z0, 0, 3328, stream);      // bn sums + mse + counts

    k0_wcvt  <<<80,    256,  0, stream>>>(Wp, Wbf);
    k1_mfma  <<<1024,  256,  0, stream>>>(s_feat, Wbf, SX, bnsum, bnsumsq);
    k2_bn    <<<1,     256,  0, stream>>>(bnsum, bnsumsq, gamma, beta, bna, bnb);
    k3_counts<<<256,   256,  0, stream>>>(gt, counts);
    k4_fused <<<256,   1024, 0, stream>>>(SX, t_feat, gt, bna, bnb, msep);
    kR_reduce<<<256,   256,  0, stream>>>(SX, gsum_s, gsumsq_s, gsum_t, gsumsq_t);
    k5_final <<<1,     256,  0, stream>>>(counts, gsum_s, gsumsq_s, gsum_t, gsumsq_t, msep, (float*)d_out);
}